// Round 9
// baseline (524.863 us; speedup 1.0000x reference)
//
#include <hip/hip_runtime.h>
#include <hip/hip_fp16.h>
#include <math.h>

#define SCALING_F 0.46211715726000974f   // tanh(0.5)
#define MAXNORM_F 0.996f                 // 1 - BALL_EPS
#define MINNORM_F 1e-15f
#define BN_EPS_F  1e-5f

// reduce over the 16-lane group holding one row
__device__ __forceinline__ float rsum16(float v) {
  v += __shfl_xor(v, 1, 64);
  v += __shfl_xor(v, 2, 64);
  v += __shfl_xor(v, 4, 64);
  v += __shfl_xor(v, 8, 64);
  return v;
}

// six independent 16-lane reductions, pipelined
__device__ __forceinline__ void rsum16x6(float& a, float& b, float& c,
                                         float& d, float& e, float& f) {
#pragma unroll
  for (int o = 1; o <= 8; o <<= 1) {
    a += __shfl_xor(a, o, 64);
    b += __shfl_xor(b, o, 64);
    c += __shfl_xor(c, o, 64);
    d += __shfl_xor(d, o, 64);
    e += __shfl_xor(e, o, 64);
    f += __shfl_xor(f, o, 64);
  }
}

// packed fp16x4 load/store (8B)
__device__ __forceinline__ void store_h4(__half* p, float v0, float v1,
                                         float v2, float v3) {
  __half2 a = __halves2half2(__float2half(v0), __float2half(v1));
  __half2 b = __halves2half2(__float2half(v2), __float2half(v3));
  uint2 u;
  u.x = *(unsigned int*)&a;
  u.y = *(unsigned int*)&b;
  *(uint2*)p = u;
}
__device__ __forceinline__ void load_h4(const __half* p, float& v0, float& v1,
                                        float& v2, float& v3) {
  uint2 u = *(const uint2*)p;
  __half2 a = *(__half2*)&u.x;
  __half2 b = *(__half2*)&u.y;
  v0 = __low2float(a); v1 = __high2float(a);
  v2 = __low2float(b); v3 = __high2float(b);
}
__device__ __forceinline__ float h2f(float v) {   // fp16 round-trip
  return __half2float(__float2half(v));
}

// ---------------------------------------------------------------------------
// mm0 (64-row tile): X = relu(x_in @ W0 + b0)  (K=128), fp16 X, fused proj:
//      Z[row] = SCALING * project(X[row])   (Z fp16)
// ---------------------------------------------------------------------------
__global__ __launch_bounds__(256) void k_mm0(
    const float* __restrict__ A, const float* __restrict__ B,
    const float* __restrict__ bias, __half* __restrict__ X,
    __half* __restrict__ Z, int M, int K)
{
  __shared__ float As[64][65];
  __shared__ float Bs[64][64];
  const int tid  = threadIdx.x;
  const int c0   = (tid & 15) * 4;
  const int r0   = (tid >> 4) * 4;
  const int rblk = blockIdx.x * 64;
  float acc[4][4] = {{0.f,0.f,0.f,0.f},{0.f,0.f,0.f,0.f},
                     {0.f,0.f,0.f,0.f},{0.f,0.f,0.f,0.f}};

  for (int kk = 0; kk < K; kk += 64) {
#pragma unroll
    for (int j = 0; j < 4; ++j) {
      int f = j * 256 + tid;
      int bk = f >> 4, bc = (f & 15) * 4;
      *(float4*)&Bs[bk][bc] = *(const float4*)&B[(size_t)(kk + bk) * 64 + bc];
    }
#pragma unroll
    for (int j = 0; j < 4; ++j) {
      int f = j * 256 + tid;
      int ar = f >> 4, ac = (f & 15) * 4;
      int row = rblk + ar;
      float4 av = make_float4(0.f, 0.f, 0.f, 0.f);
      if (row < M) av = *(const float4*)&A[(size_t)row * K + kk + ac];
      As[ar][ac + 0] = av.x;
      As[ar][ac + 1] = av.y;
      As[ar][ac + 2] = av.z;
      As[ar][ac + 3] = av.w;
    }
    __syncthreads();
#pragma unroll 16
    for (int k = 0; k < 64; ++k) {
      float4 b4 = *(float4*)&Bs[k][c0];
      float a0 = As[r0 + 0][k], a1 = As[r0 + 1][k];
      float a2 = As[r0 + 2][k], a3 = As[r0 + 3][k];
      acc[0][0] = fmaf(a0,b4.x,acc[0][0]); acc[0][1] = fmaf(a0,b4.y,acc[0][1]);
      acc[0][2] = fmaf(a0,b4.z,acc[0][2]); acc[0][3] = fmaf(a0,b4.w,acc[0][3]);
      acc[1][0] = fmaf(a1,b4.x,acc[1][0]); acc[1][1] = fmaf(a1,b4.y,acc[1][1]);
      acc[1][2] = fmaf(a1,b4.z,acc[1][2]); acc[1][3] = fmaf(a1,b4.w,acc[1][3]);
      acc[2][0] = fmaf(a2,b4.x,acc[2][0]); acc[2][1] = fmaf(a2,b4.y,acc[2][1]);
      acc[2][2] = fmaf(a2,b4.z,acc[2][2]); acc[2][3] = fmaf(a2,b4.w,acc[2][3]);
      acc[3][0] = fmaf(a3,b4.x,acc[3][0]); acc[3][1] = fmaf(a3,b4.y,acc[3][1]);
      acc[3][2] = fmaf(a3,b4.z,acc[3][2]); acc[3][3] = fmaf(a3,b4.w,acc[3][3]);
    }
    __syncthreads();
  }

  float b0 = bias[c0+0], b1 = bias[c0+1], b2 = bias[c0+2], b3 = bias[c0+3];
#pragma unroll
  for (int j = 0; j < 4; ++j) {
    int row = rblk + r0 + j;
    // round to fp16 so stored X and proj input are identical
    float v0 = h2f(fmaxf(acc[j][0] + b0, 0.f));
    float v1 = h2f(fmaxf(acc[j][1] + b1, 0.f));
    float v2 = h2f(fmaxf(acc[j][2] + b2, 0.f));
    float v3 = h2f(fmaxf(acc[j][3] + b3, 0.f));
    if (row < M)
      store_h4(&X[(size_t)row * 64 + c0], v0, v1, v2, v3);
    float sx = rsum16(v0*v0 + v1*v1 + v2*v2 + v3*v3);
    float norm = fmaxf(sqrtf(sx), MINNORM_F);
    float s = ((norm > MAXNORM_F) ? (MAXNORM_F / norm) : 1.0f) * SCALING_F;
    if (row < M)
      store_h4(&Z[(size_t)row * 64 + c0], v0*s, v1*s, v2*s, v3*s);
  }
}

// ---------------------------------------------------------------------------
// K1 (64-row tile): h = relu((x[r] + sum_nb x[nb]) @ W1 + b1), fp16 x and h,
// fused BN statistics (computed from the fp16-rounded stored h).
// ---------------------------------------------------------------------------
__global__ __launch_bounds__(256) void k_layer1(
    const __half* __restrict__ x, const int* __restrict__ rowptr,
    const int* __restrict__ csr, const float* __restrict__ B,
    const float* __restrict__ bias, __half* __restrict__ h,
    float* __restrict__ gstat, int M)
{
  __shared__ float As[64][65];
  __shared__ float Bs[64][64];
  const int tid  = threadIdx.x;
  const int c0   = (tid & 15) * 4;
  const int r0   = (tid >> 4) * 4;
  const int rblk = blockIdx.x * 64;
  const int wv   = tid >> 6;
  const int lane = tid & 63;

#pragma unroll
  for (int j = 0; j < 4; ++j) {
    int f = j * 256 + tid;
    int bk = f >> 4, bc = (f & 15) * 4;
    *(float4*)&Bs[bk][bc] = *(const float4*)&B[(size_t)bk * 64 + bc];
  }
  for (int rr = 0; rr < 16; ++rr) {
    int lr = wv * 16 + rr;
    int r  = rblk + lr;
    float acc = 0.f;
    if (r < M) {
      acc = __half2float(x[(size_t)r * 64 + lane]);
      int beg = rowptr[r], end = rowptr[r + 1];
      int j = beg;
      for (; j + 8 <= end; j += 8) {
        int n0 = csr[j+0], n1 = csr[j+1], n2 = csr[j+2], n3 = csr[j+3];
        int n4 = csr[j+4], n5 = csr[j+5], n6 = csr[j+6], n7 = csr[j+7];
        float v0 = __half2float(x[(size_t)n0*64+lane]);
        float v1 = __half2float(x[(size_t)n1*64+lane]);
        float v2 = __half2float(x[(size_t)n2*64+lane]);
        float v3 = __half2float(x[(size_t)n3*64+lane]);
        float v4 = __half2float(x[(size_t)n4*64+lane]);
        float v5 = __half2float(x[(size_t)n5*64+lane]);
        float v6 = __half2float(x[(size_t)n6*64+lane]);
        float v7 = __half2float(x[(size_t)n7*64+lane]);
        acc += ((v0+v1)+(v2+v3)) + ((v4+v5)+(v6+v7));
      }
      if (j + 4 <= end) {
        int n0 = csr[j+0], n1 = csr[j+1], n2 = csr[j+2], n3 = csr[j+3];
        float v0 = __half2float(x[(size_t)n0*64+lane]);
        float v1 = __half2float(x[(size_t)n1*64+lane]);
        float v2 = __half2float(x[(size_t)n2*64+lane]);
        float v3 = __half2float(x[(size_t)n3*64+lane]);
        acc += (v0+v1)+(v2+v3);
        j += 4;
      }
      for (; j < end; ++j) acc += __half2float(x[(size_t)csr[j]*64+lane]);
    }
    As[lr][lane] = acc;
  }
  __syncthreads();

  float acc[4][4] = {{0.f,0.f,0.f,0.f},{0.f,0.f,0.f,0.f},
                     {0.f,0.f,0.f,0.f},{0.f,0.f,0.f,0.f}};
#pragma unroll 16
  for (int k = 0; k < 64; ++k) {
    float4 b4 = *(float4*)&Bs[k][c0];
    float a0 = As[r0 + 0][k], a1 = As[r0 + 1][k];
    float a2 = As[r0 + 2][k], a3 = As[r0 + 3][k];
    acc[0][0] = fmaf(a0,b4.x,acc[0][0]); acc[0][1] = fmaf(a0,b4.y,acc[0][1]);
    acc[0][2] = fmaf(a0,b4.z,acc[0][2]); acc[0][3] = fmaf(a0,b4.w,acc[0][3]);
    acc[1][0] = fmaf(a1,b4.x,acc[1][0]); acc[1][1] = fmaf(a1,b4.y,acc[1][1]);
    acc[1][2] = fmaf(a1,b4.z,acc[1][2]); acc[1][3] = fmaf(a1,b4.w,acc[1][3]);
    acc[2][0] = fmaf(a2,b4.x,acc[2][0]); acc[2][1] = fmaf(a2,b4.y,acc[2][1]);
    acc[2][2] = fmaf(a2,b4.z,acc[2][2]); acc[2][3] = fmaf(a2,b4.w,acc[2][3]);
    acc[3][0] = fmaf(a3,b4.x,acc[3][0]); acc[3][1] = fmaf(a3,b4.y,acc[3][1]);
    acc[3][2] = fmaf(a3,b4.z,acc[3][2]); acc[3][3] = fmaf(a3,b4.w,acc[3][3]);
  }
  __syncthreads();   // Bs dead after this; reused as stats scratch

  float b0 = bias[c0+0], b1 = bias[c0+1], b2 = bias[c0+2], b3 = bias[c0+3];
  float s[4] = {0.f,0.f,0.f,0.f}, q[4] = {0.f,0.f,0.f,0.f};
#pragma unroll
  for (int j = 0; j < 4; ++j) {
    int row = rblk + r0 + j;
    if (row >= M) continue;
    // fp16-round first so stats match the stored h exactly
    float v0 = h2f(fmaxf(acc[j][0] + b0, 0.f));
    float v1 = h2f(fmaxf(acc[j][1] + b1, 0.f));
    float v2 = h2f(fmaxf(acc[j][2] + b2, 0.f));
    float v3 = h2f(fmaxf(acc[j][3] + b3, 0.f));
    s[0] += v0; s[1] += v1; s[2] += v2; s[3] += v3;
    q[0] += v0*v0; q[1] += v1*v1; q[2] += v2*v2; q[3] += v3*v3;
    store_h4(&h[(size_t)row * 64 + c0], v0, v1, v2, v3);
  }
  {
    float* st = (float*)Bs;           // [0:1024) sums, [1024:2048) sumsq
    int g = tid >> 4;
#pragma unroll
    for (int i = 0; i < 4; ++i) {
      st[g * 64 + c0 + i]        = s[i];
      st[1024 + g * 64 + c0 + i] = q[i];
    }
    __syncthreads();
    if (tid < 64) {
      float a = 0.f, b = 0.f;
#pragma unroll
      for (int g2 = 0; g2 < 16; ++g2) {
        a += st[g2 * 64 + tid];
        b += st[1024 + g2 * 64 + tid];
      }
      atomicAdd(&gstat[tid], a);
      atomicAdd(&gstat[64 + tid], b);
    }
  }
}

// ---------------------------------------------------------------------------
// K2 (64-row tile): xn = relu(BN(h) @ W2 + b2), col63 = 0; fused hyp epilogue.
// h/X/Zc/Zp/Zn all fp16 storage, all math fp32. BN scale/shift from gstat.
// If Zn != null: write X and Zn. Else (last layer): logmap0 + pool.
// ---------------------------------------------------------------------------
__global__ __launch_bounds__(256) void k_layer2(
    const __half* __restrict__ A, const float* __restrict__ B,
    const float* __restrict__ bias,
    const float* __restrict__ gstat, const float* __restrict__ gamma,
    const float* __restrict__ beta,
    __half* __restrict__ X,
    const __half* __restrict__ Zc, const __half* Zp, __half* Zn,
    const int* __restrict__ batch, float* __restrict__ pool, int M)
{
  __shared__ float As[64][65];
  __shared__ float Bs[64][64];
  __shared__ float scl_s[64], shf_s[64];
  const int tid  = threadIdx.x;
  const int c0   = (tid & 15) * 4;
  const int r0   = (tid >> 4) * 4;
  const int rblk = blockIdx.x * 64;

  if (tid < 64) {
    float mu  = gstat[tid] / (float)M;
    float var = gstat[64 + tid] / (float)M - mu * mu;
    float sv  = gamma[tid] / sqrtf(var + BN_EPS_F);
    scl_s[tid] = sv;
    shf_s[tid] = beta[tid] - mu * sv;
  }
  __syncthreads();

#pragma unroll
  for (int j = 0; j < 4; ++j) {
    int f = j * 256 + tid;
    int bk = f >> 4, bc = (f & 15) * 4;
    *(float4*)&Bs[bk][bc] = *(const float4*)&B[(size_t)bk * 64 + bc];
  }
#pragma unroll
  for (int j = 0; j < 4; ++j) {
    int f = j * 256 + tid;
    int ar = f >> 4, ac = (f & 15) * 4;
    int row = rblk + ar;
    float a0 = 0.f, a1 = 0.f, a2 = 0.f, a3 = 0.f;
    if (row < M) load_h4(&A[(size_t)row * 64 + ac], a0, a1, a2, a3);
    As[ar][ac + 0] = fmaf(a0, scl_s[ac+0], shf_s[ac+0]);
    As[ar][ac + 1] = fmaf(a1, scl_s[ac+1], shf_s[ac+1]);
    As[ar][ac + 2] = fmaf(a2, scl_s[ac+2], shf_s[ac+2]);
    As[ar][ac + 3] = fmaf(a3, scl_s[ac+3], shf_s[ac+3]);
  }

  // prefetch zc/zp so they're in flight during staging barrier + FMA loop
  float zcv4[4][4], zpv4[4][4];
#pragma unroll
  for (int j = 0; j < 4; ++j) {
    int row = rblk + r0 + j;
    zcv4[j][0] = zcv4[j][1] = zcv4[j][2] = zcv4[j][3] = 0.f;
    zpv4[j][0] = zpv4[j][1] = zpv4[j][2] = zpv4[j][3] = 0.f;
    if (row < M)
      load_h4(&Zc[(size_t)row * 64 + c0], zcv4[j][0], zcv4[j][1], zcv4[j][2], zcv4[j][3]);
    if (row < M && Zp != nullptr)
      load_h4(&Zp[(size_t)row * 64 + c0], zpv4[j][0], zpv4[j][1], zpv4[j][2], zpv4[j][3]);
  }
  __syncthreads();

  float acc[4][4] = {{0.f,0.f,0.f,0.f},{0.f,0.f,0.f,0.f},
                     {0.f,0.f,0.f,0.f},{0.f,0.f,0.f,0.f}};
#pragma unroll 16
  for (int k = 0; k < 64; ++k) {
    float4 b4 = *(float4*)&Bs[k][c0];
    float a0 = As[r0 + 0][k], a1 = As[r0 + 1][k];
    float a2 = As[r0 + 2][k], a3 = As[r0 + 3][k];
    acc[0][0] = fmaf(a0,b4.x,acc[0][0]); acc[0][1] = fmaf(a0,b4.y,acc[0][1]);
    acc[0][2] = fmaf(a0,b4.z,acc[0][2]); acc[0][3] = fmaf(a0,b4.w,acc[0][3]);
    acc[1][0] = fmaf(a1,b4.x,acc[1][0]); acc[1][1] = fmaf(a1,b4.y,acc[1][1]);
    acc[1][2] = fmaf(a1,b4.z,acc[1][2]); acc[1][3] = fmaf(a1,b4.w,acc[1][3]);
    acc[2][0] = fmaf(a2,b4.x,acc[2][0]); acc[2][1] = fmaf(a2,b4.y,acc[2][1]);
    acc[2][2] = fmaf(a2,b4.z,acc[2][2]); acc[2][3] = fmaf(a2,b4.w,acc[2][3]);
    acc[3][0] = fmaf(a3,b4.x,acc[3][0]); acc[3][1] = fmaf(a3,b4.y,acc[3][1]);
    acc[3][2] = fmaf(a3,b4.z,acc[3][2]); acc[3][3] = fmaf(a3,b4.w,acc[3][3]);
  }

  float b0 = bias[c0+0], b1 = bias[c0+1], b2 = bias[c0+2], b3 = bias[c0+3];

#pragma unroll
  for (int j = 0; j < 4; ++j) {
    int row = rblk + r0 + j;
    bool valid = (row < M);
    // fp16-round so stored X and the hyperbolic ch use identical values
    float xv[4];
    xv[0] = h2f(fmaxf(acc[j][0] + b0, 0.f));
    xv[1] = h2f(fmaxf(acc[j][1] + b1, 0.f));
    xv[2] = h2f(fmaxf(acc[j][2] + b2, 0.f));
    xv[3] = h2f(fmaxf(acc[j][3] + b3, 0.f));
    if (c0 == 60) xv[3] = 0.f;     // x[:, -1] = 0
    if (valid && X != nullptr)
      store_h4(&X[(size_t)row * 64 + c0], xv[0], xv[1], xv[2], xv[3]);

    float zcv[4] = {zcv4[j][0], zcv4[j][1], zcv4[j][2], zcv4[j][3]};
    float zpv[4] = {zpv4[j][0], zpv4[j][1], zpv4[j][2], zpv4[j][3]};

    // six independent dot-product partials
    float p1 = xv[0]*xv[0] + xv[1]*xv[1] + xv[2]*xv[2] + xv[3]*xv[3];   // Σxv²
    float p2 = zcv[0]*zcv[0]+zcv[1]*zcv[1]+zcv[2]*zcv[2]+zcv[3]*zcv[3]; // Σzc²
    float p3 = zpv[0]*zpv[0]+zpv[1]*zpv[1]+zpv[2]*zpv[2]+zpv[3]*zpv[3]; // Σzp²
    float p4 = zpv[0]*zcv[0]+zpv[1]*zcv[1]+zpv[2]*zcv[2]+zpv[3]*zcv[3]; // Σzp·zc
    float p5 = zpv[0]*xv[0]+zpv[1]*xv[1]+zpv[2]*xv[2]+zpv[3]*xv[3];     // Σzp·xv
    float p6 = zcv[0]*xv[0]+zcv[1]*xv[1]+zcv[2]*xv[2]+zcv[3]*xv[3];     // Σzc·xv
    rsum16x6(p1, p2, p3, p4, p5, p6);
    float zc63 = __shfl(zcv[3], 15, 16);   // element 63 of this row
    float zp63 = __shfl(zpv[3], 15, 16);

    // ---- scalar chain (uniform within the 16-lane group) ----
    float nzc2 = fmaxf(p2, MINNORM_F);
    float icz  = 1.0f / nzc2;
    float na2  = p2 * icz * icz;           // Σa²
    float r2   = na2 - 1.0f;
    float a63  = zc63 * icz;

    float sxn = fmaxf(sqrtf(p1), MINNORM_F);
    float sc  = ((sxn > MAXNORM_F) ? (MAXNORM_F / sxn) : 1.0f) * SCALING_F;
    float Sch2   = sc * sc * p1;           // Σch²   (ch63 = 0)
    float Szp_a  = p4 * icz;               // Σzp·a
    float Sa_ch  = sc * p6 * icz;          // Σa·ch
    float Szp_ch = sc * p5;                // Σzp·ch
    float Su_a   = Szp_a - na2;            // Σ(zp−a)·a
    float Su2    = p3 - 2.0f * Szp_a + na2;
    float nu2    = fmaxf(Su2, MINNORM_F);
    float t1     = r2 / nu2;
    float Szp22  = fmaxf(t1*t1*Su2 + 2.0f*t1*Su_a + na2, 0.0f);  // Σzp2²
    float npn    = fmaxf(sqrtf(Szp22), MINNORM_F);
    float ipn    = 1.0f / npn;
    float zp2_63 = t1 * (zp63 - a63) + a63;
    float Szp2ch = t1 * (Szp_ch - Sa_ch) + Sa_ch;
    float rdc    = -ipn * Szp2ch;          // Σr·ch  (q·ch = ch63 = 0)
    float rdr    = 1.0f - 2.0f*ipn*zp2_63 + ipn*ipn*Szp22;       // Σr·r
    float m2     = 2.0f * rdc / rdr;
    float Szp2a  = t1 * Su_a + na2;        // Σzp2·a
    float Srr_a  = a63 - ipn * Szp2a;      // Σr·a
    float Sc2a   = Sa_ch - m2 * Srr_a;     // Σc2·a
    float Sc22   = Sch2 - 2.0f*m2*rdc + m2*m2*rdr;               // Σc2²
    float Sc2ma  = Sc22 - 2.0f*Sc2a + na2; // Σ(c2−a)²
    float nu22   = fmaxf(Sc2ma, MINNORM_F);
    float t2     = r2 / nu22;

    // ---- per-lane vector tail ----
    float zn[4];
#pragma unroll
    for (int i = 0; i < 4; ++i) {
      float ai  = zcv[i] * icz;
      float zp2 = t1 * (zpv[i] - ai) + ai;
      float rri = (((c0 + i) == 63) ? 1.0f : 0.0f) - ipn * zp2;
      float c2  = sc * xv[i] - m2 * rri;
      zn[i]     = t2 * (c2 - ai) + ai;
    }

    if (Zn != nullptr) {
      if (valid)
        store_h4(&Zn[(size_t)row * 64 + c0], zn[0], zn[1], zn[2], zn[3]);
    } else {
      float Szn2 = fmaxf(t2*t2*Sc2ma + 2.0f*t2*(Sc2a - na2) + na2, 0.0f);
      float yn  = fmaxf(sqrtf(Szn2), MINNORM_F);
      float t   = fminf(yn, 1.0f);
      float ath = 0.5f * logf((1.0f + t) / (1.0f - t));
      float wsc = ath / yn;
      if (valid) {
        int b = batch[row];
        float* p = &pool[(size_t)b * 64 + c0];
        atomicAdd(p + 0, zn[0] * wsc);
        atomicAdd(p + 1, zn[1] * wsc);
        atomicAdd(p + 2, zn[2] * wsc);
        atomicAdd(p + 3, zn[3] * wsc);
      }
    }
  }
}

// ---------------------------------------------------------------------------
// CSR build
// ---------------------------------------------------------------------------
__global__ __launch_bounds__(256) void k_deg(const int* __restrict__ dst, int E, int* deg) {
  int i0 = (blockIdx.x * 256 + threadIdx.x) * 4;
  if (i0 + 4 <= E) {
    int d0 = dst[i0], d1 = dst[i0+1], d2 = dst[i0+2], d3 = dst[i0+3];
    atomicAdd(&deg[d0], 1);
    atomicAdd(&deg[d1], 1);
    atomicAdd(&deg[d2], 1);
    atomicAdd(&deg[d3], 1);
  } else {
    for (int i = i0; i < E; ++i) atomicAdd(&deg[dst[i]], 1);
  }
}

__global__ __launch_bounds__(256) void k_scan1(const int* __restrict__ deg, int N,
                                               int* rowptr, int* bsum) {
  __shared__ int s[256];
  int t = threadIdx.x;
  int i = blockIdx.x * 256 + t;
  int v = (i < N) ? deg[i] : 0;
  s[t] = v;
  __syncthreads();
  for (int d = 1; d < 256; d <<= 1) {
    int add = (t >= d) ? s[t - d] : 0;
    __syncthreads();
    s[t] += add;
    __syncthreads();
  }
  if (i < N) rowptr[i] = s[t] - v;
  if (t == 255) bsum[blockIdx.x] = s[255];
}

__global__ __launch_bounds__(256) void k_scan2(const int* __restrict__ bsum, int NB, int* boff) {
  __shared__ int s[256];
  int t = threadIdx.x;
  int v = (t < NB) ? bsum[t] : 0;
  s[t] = v;
  __syncthreads();
  for (int d = 1; d < 256; d <<= 1) {
    int add = (t >= d) ? s[t - d] : 0;
    __syncthreads();
    s[t] += add;
    __syncthreads();
  }
  boff[t] = s[t] - v;
}

__global__ __launch_bounds__(256) void k_scan3(int* rowptr, const int* __restrict__ boff,
                                               int* cursor, int N, int E) {
  int i = blockIdx.x * 256 + threadIdx.x;
  if (i < N) {
    int v = rowptr[i] + boff[blockIdx.x];
    rowptr[i] = v;
    cursor[i] = v;
  }
  if (i == 0) rowptr[N] = E;
}

__global__ __launch_bounds__(256) void k_fill(const int* __restrict__ src,
                                              const int* __restrict__ dst, int E,
                                              int* cursor, int* __restrict__ csr) {
  int i0 = (blockIdx.x * 256 + threadIdx.x) * 4;
  if (i0 + 4 <= E) {
    int d0 = dst[i0], d1 = dst[i0+1], d2 = dst[i0+2], d3 = dst[i0+3];
    int s0 = src[i0], s1 = src[i0+1], s2 = src[i0+2], s3 = src[i0+3];
    int p0 = atomicAdd(&cursor[d0], 1);
    int p1 = atomicAdd(&cursor[d1], 1);
    int p2 = atomicAdd(&cursor[d2], 1);
    int p3 = atomicAdd(&cursor[d3], 1);
    csr[p0] = s0;
    csr[p1] = s1;
    csr[p2] = s2;
    csr[p3] = s3;
  } else {
    for (int i = i0; i < E; ++i) {
      int p = atomicAdd(&cursor[dst[i]], 1);
      csr[p] = src[i];
    }
  }
}

// ---------------------------------------------------------------------------
// Per-graph MLP head + log_softmax
// ---------------------------------------------------------------------------
__global__ __launch_bounds__(128) void k_mlp(const float* __restrict__ pool,
                                             const float* __restrict__ fc1W, const float* __restrict__ fc1b,
                                             const float* __restrict__ fc2W, const float* __restrict__ fc2b,
                                             const float* __restrict__ fc3W, const float* __restrict__ fc3b,
                                             float* __restrict__ out) {
  __shared__ float p[64], o1[128], o2[64], lg[10], red[2];
  int g = blockIdx.x, t = threadIdx.x;
  if (t < 64) p[t] = pool[(size_t)g * 64 + t];
  __syncthreads();
  {
    float a = fc1b[t];
    for (int k = 0; k < 64; ++k) a = fmaf(p[k], fc1W[k * 128 + t], a);
    o1[t] = fmaxf(a, 0.f);
  }
  __syncthreads();
  if (t < 64) {
    float a = fc2b[t];
    for (int k = 0; k < 128; ++k) a = fmaf(o1[k], fc2W[k * 64 + t], a);
    o2[t] = fmaxf(a, 0.f);
  }
  __syncthreads();
  if (t < 10) {
    float a = fc3b[t];
    for (int k = 0; k < 64; ++k) a = fmaf(o2[k], fc3W[k * 10 + t], a);
    lg[t] = a;
  }
  __syncthreads();
  if (t == 0) {
    float mx = lg[0];
    for (int j = 1; j < 10; ++j) mx = fmaxf(mx, lg[j]);
    float s = 0.f;
    for (int j = 0; j < 10; ++j) s += expf(lg[j] - mx);
    red[0] = mx;
    red[1] = logf(s);
  }
  __syncthreads();
  if (t < 10) out[(size_t)g * 10 + t] = lg[t] - red[0] - red[1];
}

// ---------------------------------------------------------------------------
extern "C" void kernel_launch(void* const* d_in, const int* in_sizes, int n_in,
                              void* d_out, int out_size, void* d_ws, size_t ws_size,
                              hipStream_t stream) {
  const float* x_in  = (const float*)d_in[0];
  const int*   ei    = (const int*)d_in[1];
  const int*   batch = (const int*)d_in[2];
  const float* W0    = (const float*)d_in[3];
  const float* b0    = (const float*)d_in[4];
  const float* cW1   = (const float*)d_in[5];
  const float* cb1   = (const float*)d_in[6];
  const float* gamma = (const float*)d_in[7];
  const float* beta  = (const float*)d_in[8];
  const float* cW2   = (const float*)d_in[9];
  const float* cb2   = (const float*)d_in[10];
  const float* fc1W  = (const float*)d_in[11];
  const float* fc1b  = (const float*)d_in[12];
  const float* fc2W  = (const float*)d_in[13];
  const float* fc2b  = (const float*)d_in[14];
  const float* fc3W  = (const float*)d_in[15];
  const float* fc3b  = (const float*)d_in[16];
  float* out = (float*)d_out;

  const int N = in_sizes[0] / 128;
  const int E = in_sizes[1] / 2;
  const int L = in_sizes[5] / (64 * 64);
  const int G = out_size / 10;
  const int* src = ei;
  const int* dst = ei + E;

  char* ws = (char*)d_ws;
  size_t off = 0;
  auto alloc = [&](size_t bytes) -> char* {
    char* p = ws + off;
    off += (bytes + 255) & ~(size_t)255;
    return p;
  };
  __half* X   = (__half*)alloc((size_t)N * 64 * 2);
  __half* Bf  = (__half*)alloc((size_t)N * 64 * 2);
  __half* zb0 = (__half*)alloc((size_t)N * 64 * 2);
  __half* zb1 = (__half*)alloc((size_t)N * 64 * 2);
  __half* zb2 = (__half*)alloc((size_t)N * 64 * 2);
  // ---- zeroed region: deg, pool, gstatAll (contiguous) ----
  int*   deg  = (int*)alloc((size_t)N * 4);
  float* pool = (float*)alloc((size_t)G * 64 * 4);
  float* gstatAll = (float*)alloc((size_t)3 * 128 * 4);
  char*  zero_end = ws + off;
  // ---------------------------------------------------------
  int*   rowptr = (int*)alloc((size_t)(N + 1) * 4);
  int*   cursor = (int*)alloc((size_t)N * 4);
  int*   csr    = (int*)alloc((size_t)E * 4);
  int*   bsum   = (int*)alloc(256 * 4);
  int*   boff   = (int*)alloc(256 * 4);
  __half* zbuf[3] = {zb0, zb1, zb2};

  hipMemsetAsync(deg, 0, (size_t)(zero_end - (char*)deg), stream);

  const int mmGrid    = (N + 63) / 64;
  const int edge4Grid = (E / 4 + 255) / 256 + 1;

  // X = relu(x @ W0 + b0) (fp16); Z1 = SCALING*project(X) (fp16)
  k_mm0<<<mmGrid, 256, 0, stream>>>(x_in, W0, b0, X, zbuf[0], N, 128);

  // CSR build
  k_deg<<<edge4Grid, 256, 0, stream>>>(dst, E, deg);
  const int NB = (N + 255) / 256;
  k_scan1<<<NB, 256, 0, stream>>>(deg, N, rowptr, bsum);
  k_scan2<<<1, 256, 0, stream>>>(bsum, NB, boff);
  k_scan3<<<NB, 256, 0, stream>>>(rowptr, boff, cursor, N, E);
  k_fill<<<edge4Grid, 256, 0, stream>>>(src, dst, E, cursor, csr);

  for (int i = 0; i < L; ++i) {
    float* gstat = gstatAll + (size_t)i * 128;
    const int last = (i == L - 1);
    k_layer1<<<mmGrid, 256, 0, stream>>>(X, rowptr, csr,
                                         cW1 + (size_t)i * 64 * 64, cb1 + i * 64,
                                         Bf, gstat, N);
    k_layer2<<<mmGrid, 256, 0, stream>>>(Bf, cW2 + (size_t)i * 64 * 64, cb2 + i * 64,
                                         gstat, gamma + i * 64, beta + i * 64,
                                         last ? nullptr : X,
                                         zbuf[i],
                                         (i == 0) ? nullptr : zbuf[i - 1],
                                         last ? nullptr : zbuf[i + 1],
                                         batch, pool, N);
  }

  k_mlp<<<G, 128, 0, stream>>>(pool, fc1W, fc1b, fc2W, fc2b, fc3W, fc3b, out);
}

// Round 10
// 501.511 us; speedup vs baseline: 1.0466x; 1.0466x over previous
//
#include <hip/hip_runtime.h>
#include <hip/hip_fp16.h>
#include <math.h>

#define SCALING_F 0.46211715726000974f   // tanh(0.5)
#define MAXNORM_F 0.996f                 // 1 - BALL_EPS
#define MINNORM_F 1e-15f
#define BN_EPS_F  1e-5f

typedef _Float16 v8h __attribute__((ext_vector_type(8)));
typedef float    v4f __attribute__((ext_vector_type(4)));

// reduce over the 16-lane group holding one row
__device__ __forceinline__ float rsum16(float v) {
  v += __shfl_xor(v, 1, 64);
  v += __shfl_xor(v, 2, 64);
  v += __shfl_xor(v, 4, 64);
  v += __shfl_xor(v, 8, 64);
  return v;
}

// six independent 16-lane reductions, pipelined
__device__ __forceinline__ void rsum16x6(float& a, float& b, float& c,
                                         float& d, float& e, float& f) {
#pragma unroll
  for (int o = 1; o <= 8; o <<= 1) {
    a += __shfl_xor(a, o, 64);
    b += __shfl_xor(b, o, 64);
    c += __shfl_xor(c, o, 64);
    d += __shfl_xor(d, o, 64);
    e += __shfl_xor(e, o, 64);
    f += __shfl_xor(f, o, 64);
  }
}

__device__ __forceinline__ float h2f(float v) {   // fp16 round-trip
  return __half2float(__float2half(v));
}

// ---------------------------------------------------------------------------
// mm0 (64-row tile, MFMA): X = relu(x_in @ W0 + b0)  (K=128), fp16 X,
// fused proj: Z[row] = SCALING * project(X[row])   (Z fp16)
// ---------------------------------------------------------------------------
__global__ __launch_bounds__(256) void k_mm0(
    const float* __restrict__ A, const float* __restrict__ B,
    const float* __restrict__ bias, __half* __restrict__ X,
    __half* __restrict__ Z, int M, int K /* = 128 */)
{
  __shared__ __half AsH[64][136];   // rows of 128 halfs + pad 8 (272B, 16B-aligned)
  __shared__ __half BhT[64][136];   // BhT[n][k]
  const int tid  = threadIdx.x;
  const int w    = tid >> 6;
  const int lane = tid & 63;
  const int q    = lane >> 4;
  const int i    = lane & 15;
  const int rblk = blockIdx.x * 64;

  // stage W0^T (fp32 [128][64] -> fp16 BhT[n][k])
  for (int f = tid; f < 128 * 16; f += 256) {
    int k = f >> 4, n0 = (f & 15) * 4;
    float4 wv = *(const float4*)&B[(size_t)k * 64 + n0];
    BhT[n0 + 0][k] = __float2half(wv.x);
    BhT[n0 + 1][k] = __float2half(wv.y);
    BhT[n0 + 2][k] = __float2half(wv.z);
    BhT[n0 + 3][k] = __float2half(wv.w);
  }
  // stage A rows fp32 -> fp16
  for (int f = tid; f < 64 * 32; f += 256) {
    int ar = f >> 5, ac = (f & 31) * 4;
    int row = rblk + ar;
    float4 av = make_float4(0.f, 0.f, 0.f, 0.f);
    if (row < M) av = *(const float4*)&A[(size_t)row * K + ac];
    AsH[ar][ac + 0] = __float2half(av.x);
    AsH[ar][ac + 1] = __float2half(av.y);
    AsH[ar][ac + 2] = __float2half(av.z);
    AsH[ar][ac + 3] = __float2half(av.w);
  }
  __syncthreads();

  v4f acc[4];
#pragma unroll
  for (int t = 0; t < 4; ++t) acc[t] = (v4f){0.f, 0.f, 0.f, 0.f};
#pragma unroll
  for (int h = 0; h < 4; ++h) {
    v8h af = *(const v8h*)&AsH[w * 16 + i][h * 32 + q * 8];
#pragma unroll
    for (int t = 0; t < 4; ++t) {
      v8h bf = *(const v8h*)&BhT[t * 16 + i][h * 32 + q * 8];
      acc[t] = __builtin_amdgcn_mfma_f32_16x16x32_f16(af, bf, acc[t], 0, 0, 0);
    }
  }

  // epilogue: row = rblk + w*16 + 4q + j, cols = i + 16t
#pragma unroll
  for (int j = 0; j < 4; ++j) {
    int row = rblk + w * 16 + 4 * q + j;
    bool valid = (row < M);
    float xv[4];
#pragma unroll
    for (int t = 0; t < 4; ++t)
      xv[t] = h2f(fmaxf(acc[t][j] + bias[i + 16 * t], 0.f));
    if (valid) {
#pragma unroll
      for (int t = 0; t < 4; ++t)
        X[(size_t)row * 64 + i + 16 * t] = __float2half(xv[t]);
    }
    float sx = rsum16(xv[0]*xv[0] + xv[1]*xv[1] + xv[2]*xv[2] + xv[3]*xv[3]);
    float norm = fmaxf(sqrtf(sx), MINNORM_F);
    float s = ((norm > MAXNORM_F) ? (MAXNORM_F / norm) : 1.0f) * SCALING_F;
    if (valid) {
#pragma unroll
      for (int t = 0; t < 4; ++t)
        Z[(size_t)row * 64 + i + 16 * t] = __float2half(xv[t] * s);
    }
  }
}

// ---------------------------------------------------------------------------
// K1 (64-row tile, MFMA): h = relu((x[r] + sum_nb x[nb]) @ W1 + b1),
// fp16 x and h, fused BN statistics (from the fp16-rounded stored h).
// ---------------------------------------------------------------------------
__global__ __launch_bounds__(256) void k_layer1(
    const __half* __restrict__ x, const int* __restrict__ rowptr,
    const int* __restrict__ csr, const float* __restrict__ B,
    const float* __restrict__ bias, __half* __restrict__ h,
    float* __restrict__ gstat, int M)
{
  __shared__ __half AsH[64][72];   // 144B rows, 16B-aligned
  __shared__ __half BhT[64][72];
  const int tid  = threadIdx.x;
  const int w    = tid >> 6;
  const int lane = tid & 63;
  const int q    = lane >> 4;
  const int i    = lane & 15;
  const int rblk = blockIdx.x * 64;

  // stage W1^T
  for (int f = tid; f < 64 * 16; f += 256) {
    int k = f >> 4, n0 = (f & 15) * 4;
    float4 wv = *(const float4*)&B[(size_t)k * 64 + n0];
    BhT[n0 + 0][k] = __float2half(wv.x);
    BhT[n0 + 1][k] = __float2half(wv.y);
    BhT[n0 + 2][k] = __float2half(wv.z);
    BhT[n0 + 3][k] = __float2half(wv.w);
  }
  // gather-stage A (fp32 accumulate, fp16 store)
  for (int rr = 0; rr < 16; ++rr) {
    int lr = w * 16 + rr;
    int r  = rblk + lr;
    float acc = 0.f;
    if (r < M) {
      acc = __half2float(x[(size_t)r * 64 + lane]);
      int beg = rowptr[r], end = rowptr[r + 1];
      int j = beg;
      for (; j + 8 <= end; j += 8) {
        int n0 = csr[j+0], n1 = csr[j+1], n2 = csr[j+2], n3 = csr[j+3];
        int n4 = csr[j+4], n5 = csr[j+5], n6 = csr[j+6], n7 = csr[j+7];
        float v0 = __half2float(x[(size_t)n0*64+lane]);
        float v1 = __half2float(x[(size_t)n1*64+lane]);
        float v2 = __half2float(x[(size_t)n2*64+lane]);
        float v3 = __half2float(x[(size_t)n3*64+lane]);
        float v4 = __half2float(x[(size_t)n4*64+lane]);
        float v5 = __half2float(x[(size_t)n5*64+lane]);
        float v6 = __half2float(x[(size_t)n6*64+lane]);
        float v7 = __half2float(x[(size_t)n7*64+lane]);
        acc += ((v0+v1)+(v2+v3)) + ((v4+v5)+(v6+v7));
      }
      if (j + 4 <= end) {
        int n0 = csr[j+0], n1 = csr[j+1], n2 = csr[j+2], n3 = csr[j+3];
        float v0 = __half2float(x[(size_t)n0*64+lane]);
        float v1 = __half2float(x[(size_t)n1*64+lane]);
        float v2 = __half2float(x[(size_t)n2*64+lane]);
        float v3 = __half2float(x[(size_t)n3*64+lane]);
        acc += (v0+v1)+(v2+v3);
        j += 4;
      }
      for (; j < end; ++j) acc += __half2float(x[(size_t)csr[j]*64+lane]);
    }
    AsH[lr][lane] = __float2half(acc);
  }
  __syncthreads();

  v4f acc[4];
#pragma unroll
  for (int t = 0; t < 4; ++t) acc[t] = (v4f){0.f, 0.f, 0.f, 0.f};
#pragma unroll
  for (int hh = 0; hh < 2; ++hh) {
    v8h af = *(const v8h*)&AsH[w * 16 + i][hh * 32 + q * 8];
#pragma unroll
    for (int t = 0; t < 4; ++t) {
      v8h bf = *(const v8h*)&BhT[t * 16 + i][hh * 32 + q * 8];
      acc[t] = __builtin_amdgcn_mfma_f32_16x16x32_f16(af, bf, acc[t], 0, 0, 0);
    }
  }
  __syncthreads();   // BhT dead; reuse as stats scratch

  float s[4] = {0.f, 0.f, 0.f, 0.f}, qq[4] = {0.f, 0.f, 0.f, 0.f};
#pragma unroll
  for (int j = 0; j < 4; ++j) {
    int row = rblk + w * 16 + 4 * q + j;
    if (row >= M) continue;
#pragma unroll
    for (int t = 0; t < 4; ++t) {
      float v = h2f(fmaxf(acc[t][j] + bias[i + 16 * t], 0.f));
      h[(size_t)row * 64 + i + 16 * t] = __float2half(v);
      s[t] += v;
      qq[t] += v * v;
    }
  }
  {
    float* st = (float*)BhT;           // [0:1024) sums, [1024:2048) sumsq
    int g = w * 4 + q;                 // 16 row-groups
#pragma unroll
    for (int t = 0; t < 4; ++t) {
      st[g * 64 + i + 16 * t]        = s[t];
      st[1024 + g * 64 + i + 16 * t] = qq[t];
    }
    __syncthreads();
    if (tid < 64) {
      float a = 0.f, b = 0.f;
#pragma unroll
      for (int g2 = 0; g2 < 16; ++g2) {
        a += st[g2 * 64 + tid];
        b += st[1024 + g2 * 64 + tid];
      }
      atomicAdd(&gstat[tid], a);
      atomicAdd(&gstat[64 + tid], b);
    }
  }
}

// ---------------------------------------------------------------------------
// K2 (64-row tile, MFMA): xn = relu(BN(h) @ W2 + b2), col63 = 0; fused hyp.
// h/X/Zc/Zp/Zn fp16 storage, math fp32. BN scale/shift from gstat in-block.
// If Zn != null: write X and Zn. Else (last layer): logmap0 + pool.
// ---------------------------------------------------------------------------
__global__ __launch_bounds__(256) void k_layer2(
    const __half* __restrict__ A, const float* __restrict__ B,
    const float* __restrict__ bias,
    const float* __restrict__ gstat, const float* __restrict__ gamma,
    const float* __restrict__ beta,
    __half* __restrict__ X,
    const __half* __restrict__ Zc, const __half* Zp, __half* Zn,
    const int* __restrict__ batch, float* __restrict__ pool, int M)
{
  __shared__ __half AsH[64][72];
  __shared__ __half BhT[64][72];
  __shared__ float scl_s[64], shf_s[64];
  const int tid  = threadIdx.x;
  const int w    = tid >> 6;
  const int lane = tid & 63;
  const int q    = lane >> 4;
  const int i    = lane & 15;
  const int rblk = blockIdx.x * 64;

  if (tid < 64) {
    float mu  = gstat[tid] / (float)M;
    float var = gstat[64 + tid] / (float)M - mu * mu;
    float sv  = gamma[tid] / sqrtf(var + BN_EPS_F);
    scl_s[tid] = sv;
    shf_s[tid] = beta[tid] - mu * sv;
  }
  __syncthreads();

  // stage W2^T
  for (int f = tid; f < 64 * 16; f += 256) {
    int k = f >> 4, n0 = (f & 15) * 4;
    float4 wv = *(const float4*)&B[(size_t)k * 64 + n0];
    BhT[n0 + 0][k] = __float2half(wv.x);
    BhT[n0 + 1][k] = __float2half(wv.y);
    BhT[n0 + 2][k] = __float2half(wv.z);
    BhT[n0 + 3][k] = __float2half(wv.w);
  }
  // stage BN(h) -> fp16 A
  for (int f = tid; f < 64 * 16; f += 256) {
    int ar = f >> 4, ac = (f & 15) * 4;
    int row = rblk + ar;
    float a0 = 0.f, a1 = 0.f, a2 = 0.f, a3 = 0.f;
    if (row < M) {
      uint2 u = *(const uint2*)&A[(size_t)row * 64 + ac];
      __half2 ha = *(__half2*)&u.x;
      __half2 hb = *(__half2*)&u.y;
      a0 = __low2float(ha); a1 = __high2float(ha);
      a2 = __low2float(hb); a3 = __high2float(hb);
    }
    AsH[ar][ac + 0] = __float2half(fmaf(a0, scl_s[ac+0], shf_s[ac+0]));
    AsH[ar][ac + 1] = __float2half(fmaf(a1, scl_s[ac+1], shf_s[ac+1]));
    AsH[ar][ac + 2] = __float2half(fmaf(a2, scl_s[ac+2], shf_s[ac+2]));
    AsH[ar][ac + 3] = __float2half(fmaf(a3, scl_s[ac+3], shf_s[ac+3]));
  }

  // prefetch zc/zp (per-lane cols i+16t for my 4 rows) before the barrier
  float zcv4[4][4], zpv4[4][4];
#pragma unroll
  for (int j = 0; j < 4; ++j) {
    int row = rblk + w * 16 + 4 * q + j;
    bool valid = (row < M);
#pragma unroll
    for (int t = 0; t < 4; ++t) {
      zcv4[j][t] = valid ? __half2float(Zc[(size_t)row * 64 + i + 16 * t]) : 0.f;
      zpv4[j][t] = (valid && Zp != nullptr)
                     ? __half2float(Zp[(size_t)row * 64 + i + 16 * t]) : 0.f;
    }
  }
  __syncthreads();

  v4f acc[4];
#pragma unroll
  for (int t = 0; t < 4; ++t) acc[t] = (v4f){0.f, 0.f, 0.f, 0.f};
#pragma unroll
  for (int hh = 0; hh < 2; ++hh) {
    v8h af = *(const v8h*)&AsH[w * 16 + i][hh * 32 + q * 8];
#pragma unroll
    for (int t = 0; t < 4; ++t) {
      v8h bf = *(const v8h*)&BhT[t * 16 + i][hh * 32 + q * 8];
      acc[t] = __builtin_amdgcn_mfma_f32_16x16x32_f16(af, bf, acc[t], 0, 0, 0);
    }
  }

#pragma unroll
  for (int j = 0; j < 4; ++j) {
    int row = rblk + w * 16 + 4 * q + j;
    bool valid = (row < M);
    float xv[4];
#pragma unroll
    for (int t = 0; t < 4; ++t)
      xv[t] = h2f(fmaxf(acc[t][j] + bias[i + 16 * t], 0.f));
    if (i == 15) xv[3] = 0.f;          // col 63: x[:, -1] = 0
    if (valid && X != nullptr) {
#pragma unroll
      for (int t = 0; t < 4; ++t)
        X[(size_t)row * 64 + i + 16 * t] = __float2half(xv[t]);
    }

    float zcv[4] = {zcv4[j][0], zcv4[j][1], zcv4[j][2], zcv4[j][3]};
    float zpv[4] = {zpv4[j][0], zpv4[j][1], zpv4[j][2], zpv4[j][3]};

    float p1 = xv[0]*xv[0] + xv[1]*xv[1] + xv[2]*xv[2] + xv[3]*xv[3];   // Σxv²
    float p2 = zcv[0]*zcv[0]+zcv[1]*zcv[1]+zcv[2]*zcv[2]+zcv[3]*zcv[3]; // Σzc²
    float p3 = zpv[0]*zpv[0]+zpv[1]*zpv[1]+zpv[2]*zpv[2]+zpv[3]*zpv[3]; // Σzp²
    float p4 = zpv[0]*zcv[0]+zpv[1]*zcv[1]+zpv[2]*zcv[2]+zpv[3]*zcv[3]; // Σzp·zc
    float p5 = zpv[0]*xv[0]+zpv[1]*xv[1]+zpv[2]*xv[2]+zpv[3]*xv[3];     // Σzp·xv
    float p6 = zcv[0]*xv[0]+zcv[1]*xv[1]+zcv[2]*xv[2]+zcv[3]*xv[3];     // Σzc·xv
    rsum16x6(p1, p2, p3, p4, p5, p6);
    float zc63 = __shfl(zcv[3], 15, 16);   // col 63 = lane i=15, t=3
    float zp63 = __shfl(zpv[3], 15, 16);

    float nzc2 = fmaxf(p2, MINNORM_F);
    float icz  = 1.0f / nzc2;
    float na2  = p2 * icz * icz;           // Σa²
    float r2   = na2 - 1.0f;
    float a63  = zc63 * icz;

    float sxn = fmaxf(sqrtf(p1), MINNORM_F);
    float sc  = ((sxn > MAXNORM_F) ? (MAXNORM_F / sxn) : 1.0f) * SCALING_F;
    float Sch2   = sc * sc * p1;           // Σch² (ch63 = 0)
    float Szp_a  = p4 * icz;
    float Sa_ch  = sc * p6 * icz;
    float Szp_ch = sc * p5;
    float Su_a   = Szp_a - na2;
    float Su2    = p3 - 2.0f * Szp_a + na2;
    float nu2    = fmaxf(Su2, MINNORM_F);
    float t1     = r2 / nu2;
    float Szp22  = fmaxf(t1*t1*Su2 + 2.0f*t1*Su_a + na2, 0.0f);
    float npn    = fmaxf(sqrtf(Szp22), MINNORM_F);
    float ipn    = 1.0f / npn;
    float zp2_63 = t1 * (zp63 - a63) + a63;
    float Szp2ch = t1 * (Szp_ch - Sa_ch) + Sa_ch;
    float rdc    = -ipn * Szp2ch;
    float rdr    = 1.0f - 2.0f*ipn*zp2_63 + ipn*ipn*Szp22;
    float m2     = 2.0f * rdc / rdr;
    float Szp2a  = t1 * Su_a + na2;
    float Srr_a  = a63 - ipn * Szp2a;
    float Sc2a   = Sa_ch - m2 * Srr_a;
    float Sc22   = Sch2 - 2.0f*m2*rdc + m2*m2*rdr;
    float Sc2ma  = Sc22 - 2.0f*Sc2a + na2;
    float nu22   = fmaxf(Sc2ma, MINNORM_F);
    float t2     = r2 / nu22;

    float zn[4];
#pragma unroll
    for (int t = 0; t < 4; ++t) {
      float ai  = zcv[t] * icz;
      float zp2 = t1 * (zpv[t] - ai) + ai;
      float rri = ((i == 15 && t == 3) ? 1.0f : 0.0f) - ipn * zp2;
      float c2  = sc * xv[t] - m2 * rri;
      zn[t]     = t2 * (c2 - ai) + ai;
    }

    if (Zn != nullptr) {
      if (valid) {
#pragma unroll
        for (int t = 0; t < 4; ++t)
          Zn[(size_t)row * 64 + i + 16 * t] = __float2half(zn[t]);
      }
    } else {
      float Szn2 = fmaxf(t2*t2*Sc2ma + 2.0f*t2*(Sc2a - na2) + na2, 0.0f);
      float yn  = fmaxf(sqrtf(Szn2), MINNORM_F);
      float t   = fminf(yn, 1.0f);
      float ath = 0.5f * logf((1.0f + t) / (1.0f - t));
      float wsc = ath / yn;
      if (valid) {
        int b = batch[row];
        float* p = &pool[(size_t)b * 64 + i];
#pragma unroll
        for (int t4 = 0; t4 < 4; ++t4)
          atomicAdd(p + 16 * t4, zn[t4] * wsc);
      }
    }
  }
}

// ---------------------------------------------------------------------------
// CSR build
// ---------------------------------------------------------------------------
__global__ __launch_bounds__(256) void k_deg(const int* __restrict__ dst, int E, int* deg) {
  int i0 = (blockIdx.x * 256 + threadIdx.x) * 4;
  if (i0 + 4 <= E) {
    int d0 = dst[i0], d1 = dst[i0+1], d2 = dst[i0+2], d3 = dst[i0+3];
    atomicAdd(&deg[d0], 1);
    atomicAdd(&deg[d1], 1);
    atomicAdd(&deg[d2], 1);
    atomicAdd(&deg[d3], 1);
  } else {
    for (int i = i0; i < E; ++i) atomicAdd(&deg[dst[i]], 1);
  }
}

__global__ __launch_bounds__(256) void k_scan1(const int* __restrict__ deg, int N,
                                               int* rowptr, int* bsum) {
  __shared__ int s[256];
  int t = threadIdx.x;
  int i = blockIdx.x * 256 + t;
  int v = (i < N) ? deg[i] : 0;
  s[t] = v;
  __syncthreads();
  for (int d = 1; d < 256; d <<= 1) {
    int add = (t >= d) ? s[t - d] : 0;
    __syncthreads();
    s[t] += add;
    __syncthreads();
  }
  if (i < N) rowptr[i] = s[t] - v;
  if (t == 255) bsum[blockIdx.x] = s[255];
}

__global__ __launch_bounds__(256) void k_scan2(const int* __restrict__ bsum, int NB, int* boff) {
  __shared__ int s[256];
  int t = threadIdx.x;
  int v = (t < NB) ? bsum[t] : 0;
  s[t] = v;
  __syncthreads();
  for (int d = 1; d < 256; d <<= 1) {
    int add = (t >= d) ? s[t - d] : 0;
    __syncthreads();
    s[t] += add;
    __syncthreads();
  }
  boff[t] = s[t] - v;
}

__global__ __launch_bounds__(256) void k_scan3(int* rowptr, const int* __restrict__ boff,
                                               int* cursor, int N, int E) {
  int i = blockIdx.x * 256 + threadIdx.x;
  if (i < N) {
    int v = rowptr[i] + boff[blockIdx.x];
    rowptr[i] = v;
    cursor[i] = v;
  }
  if (i == 0) rowptr[N] = E;
}

__global__ __launch_bounds__(256) void k_fill(const int* __restrict__ src,
                                              const int* __restrict__ dst, int E,
                                              int* cursor, int* __restrict__ csr) {
  int i0 = (blockIdx.x * 256 + threadIdx.x) * 4;
  if (i0 + 4 <= E) {
    int d0 = dst[i0], d1 = dst[i0+1], d2 = dst[i0+2], d3 = dst[i0+3];
    int s0 = src[i0], s1 = src[i0+1], s2 = src[i0+2], s3 = src[i0+3];
    int p0 = atomicAdd(&cursor[d0], 1);
    int p1 = atomicAdd(&cursor[d1], 1);
    int p2 = atomicAdd(&cursor[d2], 1);
    int p3 = atomicAdd(&cursor[d3], 1);
    csr[p0] = s0;
    csr[p1] = s1;
    csr[p2] = s2;
    csr[p3] = s3;
  } else {
    for (int i = i0; i < E; ++i) {
      int p = atomicAdd(&cursor[dst[i]], 1);
      csr[p] = src[i];
    }
  }
}

// ---------------------------------------------------------------------------
// Per-graph MLP head + log_softmax
// ---------------------------------------------------------------------------
__global__ __launch_bounds__(128) void k_mlp(const float* __restrict__ pool,
                                             const float* __restrict__ fc1W, const float* __restrict__ fc1b,
                                             const float* __restrict__ fc2W, const float* __restrict__ fc2b,
                                             const float* __restrict__ fc3W, const float* __restrict__ fc3b,
                                             float* __restrict__ out) {
  __shared__ float p[64], o1[128], o2[64], lg[10], red[2];
  int g = blockIdx.x, t = threadIdx.x;
  if (t < 64) p[t] = pool[(size_t)g * 64 + t];
  __syncthreads();
  {
    float a = fc1b[t];
    for (int k = 0; k < 64; ++k) a = fmaf(p[k], fc1W[k * 128 + t], a);
    o1[t] = fmaxf(a, 0.f);
  }
  __syncthreads();
  if (t < 64) {
    float a = fc2b[t];
    for (int k = 0; k < 128; ++k) a = fmaf(o1[k], fc2W[k * 64 + t], a);
    o2[t] = fmaxf(a, 0.f);
  }
  __syncthreads();
  if (t < 10) {
    float a = fc3b[t];
    for (int k = 0; k < 64; ++k) a = fmaf(o2[k], fc3W[k * 10 + t], a);
    lg[t] = a;
  }
  __syncthreads();
  if (t == 0) {
    float mx = lg[0];
    for (int j = 1; j < 10; ++j) mx = fmaxf(mx, lg[j]);
    float s = 0.f;
    for (int j = 0; j < 10; ++j) s += expf(lg[j] - mx);
    red[0] = mx;
    red[1] = logf(s);
  }
  __syncthreads();
  if (t < 10) out[(size_t)g * 10 + t] = lg[t] - red[0] - red[1];
}

// ---------------------------------------------------------------------------
extern "C" void kernel_launch(void* const* d_in, const int* in_sizes, int n_in,
                              void* d_out, int out_size, void* d_ws, size_t ws_size,
                              hipStream_t stream) {
  const float* x_in  = (const float*)d_in[0];
  const int*   ei    = (const int*)d_in[1];
  const int*   batch = (const int*)d_in[2];
  const float* W0    = (const float*)d_in[3];
  const float* b0    = (const float*)d_in[4];
  const float* cW1   = (const float*)d_in[5];
  const float* cb1   = (const float*)d_in[6];
  const float* gamma = (const float*)d_in[7];
  const float* beta  = (const float*)d_in[8];
  const float* cW2   = (const float*)d_in[9];
  const float* cb2   = (const float*)d_in[10];
  const float* fc1W  = (const float*)d_in[11];
  const float* fc1b  = (const float*)d_in[12];
  const float* fc2W  = (const float*)d_in[13];
  const float* fc2b  = (const float*)d_in[14];
  const float* fc3W  = (const float*)d_in[15];
  const float* fc3b  = (const float*)d_in[16];
  float* out = (float*)d_out;

  const int N = in_sizes[0] / 128;
  const int E = in_sizes[1] / 2;
  const int L = in_sizes[5] / (64 * 64);
  const int G = out_size / 10;
  const int* src = ei;
  const int* dst = ei + E;

  char* ws = (char*)d_ws;
  size_t off = 0;
  auto alloc = [&](size_t bytes) -> char* {
    char* p = ws + off;
    off += (bytes + 255) & ~(size_t)255;
    return p;
  };
  __half* X   = (__half*)alloc((size_t)N * 64 * 2);
  __half* Bf  = (__half*)alloc((size_t)N * 64 * 2);
  __half* zb0 = (__half*)alloc((size_t)N * 64 * 2);
  __half* zb1 = (__half*)alloc((size_t)N * 64 * 2);
  __half* zb2 = (__half*)alloc((size_t)N * 64 * 2);
  // ---- zeroed region: deg, pool, gstatAll (contiguous) ----
  int*   deg  = (int*)alloc((size_t)N * 4);
  float* pool = (float*)alloc((size_t)G * 64 * 4);
  float* gstatAll = (float*)alloc((size_t)3 * 128 * 4);
  char*  zero_end = ws + off;
  // ---------------------------------------------------------
  int*   rowptr = (int*)alloc((size_t)(N + 1) * 4);
  int*   cursor = (int*)alloc((size_t)N * 4);
  int*   csr    = (int*)alloc((size_t)E * 4);
  int*   bsum   = (int*)alloc(256 * 4);
  int*   boff   = (int*)alloc(256 * 4);
  __half* zbuf[3] = {zb0, zb1, zb2};

  hipMemsetAsync(deg, 0, (size_t)(zero_end - (char*)deg), stream);

  const int mmGrid    = (N + 63) / 64;
  const int edge4Grid = (E / 4 + 255) / 256 + 1;

  // X = relu(x @ W0 + b0) (fp16); Z1 = SCALING*project(X) (fp16)
  k_mm0<<<mmGrid, 256, 0, stream>>>(x_in, W0, b0, X, zbuf[0], N, 128);

  // CSR build
  k_deg<<<edge4Grid, 256, 0, stream>>>(dst, E, deg);
  const int NB = (N + 255) / 256;
  k_scan1<<<NB, 256, 0, stream>>>(deg, N, rowptr, bsum);
  k_scan2<<<1, 256, 0, stream>>>(bsum, NB, boff);
  k_scan3<<<NB, 256, 0, stream>>>(rowptr, boff, cursor, N, E);
  k_fill<<<edge4Grid, 256, 0, stream>>>(src, dst, E, cursor, csr);

  for (int i = 0; i < L; ++i) {
    float* gstat = gstatAll + (size_t)i * 128;
    const int last = (i == L - 1);
    k_layer1<<<mmGrid, 256, 0, stream>>>(X, rowptr, csr,
                                         cW1 + (size_t)i * 64 * 64, cb1 + i * 64,
                                         Bf, gstat, N);
    k_layer2<<<mmGrid, 256, 0, stream>>>(Bf, cW2 + (size_t)i * 64 * 64, cb2 + i * 64,
                                         gstat, gamma + i * 64, beta + i * 64,
                                         last ? nullptr : X,
                                         zbuf[i],
                                         (i == 0) ? nullptr : zbuf[i - 1],
                                         last ? nullptr : zbuf[i + 1],
                                         batch, pool, N);
  }

  k_mlp<<<G, 128, 0, stream>>>(pool, fc1W, fc1b, fc2W, fc2b, fc3W, fc3b, out);
}

// Round 11
// 477.499 us; speedup vs baseline: 1.0992x; 1.0503x over previous
//
#include <hip/hip_runtime.h>
#include <hip/hip_fp16.h>
#include <math.h>

#define SCALING_F 0.46211715726000974f   // tanh(0.5)
#define MAXNORM_F 0.996f                 // 1 - BALL_EPS
#define MINNORM_F 1e-15f
#define BN_EPS_F  1e-5f

typedef _Float16 v8h __attribute__((ext_vector_type(8)));
typedef float    v4f __attribute__((ext_vector_type(4)));

// reduce over the 16-lane group holding one row
__device__ __forceinline__ float rsum16(float v) {
  v += __shfl_xor(v, 1, 64);
  v += __shfl_xor(v, 2, 64);
  v += __shfl_xor(v, 4, 64);
  v += __shfl_xor(v, 8, 64);
  return v;
}

__device__ __forceinline__ void rsum16x6(float& a, float& b, float& c,
                                         float& d, float& e, float& f) {
#pragma unroll
  for (int o = 1; o <= 8; o <<= 1) {
    a += __shfl_xor(a, o, 64);
    b += __shfl_xor(b, o, 64);
    c += __shfl_xor(c, o, 64);
    d += __shfl_xor(d, o, 64);
    e += __shfl_xor(e, o, 64);
    f += __shfl_xor(f, o, 64);
  }
}

__device__ __forceinline__ float h2f(float v) {   // fp16 round-trip
  return __half2float(__float2half(v));
}

// accumulate 8 halfs (as uint4) into float[8]
__device__ __forceinline__ void acc8(float* a, uint4 u) {
  __half2 h0 = *(__half2*)&u.x;
  __half2 h1 = *(__half2*)&u.y;
  __half2 h2 = *(__half2*)&u.z;
  __half2 h3 = *(__half2*)&u.w;
  a[0] += __low2float(h0); a[1] += __high2float(h0);
  a[2] += __low2float(h1); a[3] += __high2float(h1);
  a[4] += __low2float(h2); a[5] += __high2float(h2);
  a[6] += __low2float(h3); a[7] += __high2float(h3);
}

// ---------------------------------------------------------------------------
// One-time weight conversion: fp32 row-major [K][64] -> fp16 transposed [n][k]
// ---------------------------------------------------------------------------
__global__ __launch_bounds__(256) void k_wcvt(
    const float* __restrict__ W0, const float* __restrict__ cW1,
    const float* __restrict__ cW2, int L,
    __half* __restrict__ W0T, __half* __restrict__ W1T, __half* __restrict__ W2T)
{
  int id = blockIdx.x * 256 + threadIdx.x;
  if (id < 64 * 128) {            // W0T[n][k], k<128
    int n = id >> 7, k = id & 127;
    W0T[id] = __float2half(W0[(size_t)k * 64 + n]);
  }
  if (id < L * 64 * 64) {         // W1T/W2T[l][n][k]
    int l = id >> 12, rem = id & 4095;
    int n = rem >> 6, k = rem & 63;
    W1T[id] = __float2half(cW1[(size_t)l * 4096 + k * 64 + n]);
    W2T[id] = __float2half(cW2[(size_t)l * 4096 + k * 64 + n]);
  }
}

// ---------------------------------------------------------------------------
// mm0 (64-row tile, MFMA, no LDS): X = relu(x_in @ W0 + b0) (K=128, fp16 X),
// fused proj: Z[row] = SCALING * project(X[row])  (fp16)
// ---------------------------------------------------------------------------
__global__ __launch_bounds__(256) void k_mm0(
    const float* __restrict__ A, const __half* __restrict__ BT,
    const float* __restrict__ bias, __half* __restrict__ X,
    __half* __restrict__ Z, int M)
{
  const int tid  = threadIdx.x;
  const int w    = tid >> 6;
  const int lane = tid & 63;
  const int q    = lane >> 4;
  const int i    = lane & 15;
  const int rblk = blockIdx.x * 64;
  const int arow = rblk + w * 16 + i;     // A-operand row for this lane

  v4f acc[4];
#pragma unroll
  for (int t = 0; t < 4; ++t) acc[t] = (v4f){0.f, 0.f, 0.f, 0.f};

#pragma unroll
  for (int hh = 0; hh < 4; ++hh) {
    v8h af = (v8h){0, 0, 0, 0, 0, 0, 0, 0};
    if (arow < M) {
      const float* p = &A[(size_t)arow * 128 + hh * 32 + q * 8];
      float4 fa = *(const float4*)p;
      float4 fb = *(const float4*)(p + 4);
      af[0] = (_Float16)fa.x; af[1] = (_Float16)fa.y;
      af[2] = (_Float16)fa.z; af[3] = (_Float16)fa.w;
      af[4] = (_Float16)fb.x; af[5] = (_Float16)fb.y;
      af[6] = (_Float16)fb.z; af[7] = (_Float16)fb.w;
    }
#pragma unroll
    for (int t = 0; t < 4; ++t) {
      v8h bf = *(const v8h*)&BT[(size_t)(t * 16 + i) * 128 + hh * 32 + q * 8];
      acc[t] = __builtin_amdgcn_mfma_f32_16x16x32_f16(af, bf, acc[t], 0, 0, 0);
    }
  }

#pragma unroll
  for (int j = 0; j < 4; ++j) {
    int row = rblk + w * 16 + 4 * q + j;
    bool valid = (row < M);
    float xv[4];
#pragma unroll
    for (int t = 0; t < 4; ++t)
      xv[t] = h2f(fmaxf(acc[t][j] + bias[i + 16 * t], 0.f));
    if (valid) {
#pragma unroll
      for (int t = 0; t < 4; ++t)
        X[(size_t)row * 64 + i + 16 * t] = __float2half(xv[t]);
    }
    float sx = rsum16(xv[0]*xv[0] + xv[1]*xv[1] + xv[2]*xv[2] + xv[3]*xv[3]);
    float norm = fmaxf(sqrtf(sx), MINNORM_F);
    float s = ((norm > MAXNORM_F) ? (MAXNORM_F / norm) : 1.0f) * SCALING_F;
    if (valid) {
#pragma unroll
      for (int t = 0; t < 4; ++t)
        Z[(size_t)row * 64 + i + 16 * t] = __float2half(xv[t] * s);
    }
  }
}

// ---------------------------------------------------------------------------
// K1 (64-row tile, MFMA): h = relu((x[r] + sum_nb x[nb]) @ W1 + b1),
// fp16 x/h, fused BN stats. Gather: 8 neighbors per wave-load (16B/lane),
// cross-group combine via 3 shfl_xor steps. B-frags direct from global.
// ---------------------------------------------------------------------------
__global__ __launch_bounds__(256) void k_layer1(
    const __half* __restrict__ x, const int* __restrict__ rowptr,
    const int* __restrict__ csr, const __half* __restrict__ BT,
    const float* __restrict__ bias, __half* __restrict__ h,
    float* __restrict__ gstat, int M)
{
  __shared__ __half AsH[64][80];   // 160B rows (16B aligned)
  __shared__ float st[2048];
  const int tid  = threadIdx.x;
  const int w    = tid >> 6;
  const int lane = tid & 63;
  const int q    = lane >> 4;
  const int i    = lane & 15;
  const int g8   = lane >> 3;      // neighbor slot 0..7
  const int i8   = lane & 7;       // col group: cols 8*i8 .. +8
  const int rblk = blockIdx.x * 64;

  // gather-stage A: one wave per 16 rows; 8 neighbors per load iteration
  for (int rr = 0; rr < 16; ++rr) {
    int lr = w * 16 + rr;
    int r  = rblk + lr;
    float a[8] = {0.f,0.f,0.f,0.f,0.f,0.f,0.f,0.f};
    if (r < M) {
      if (g8 == 0)
        acc8(a, *(const uint4*)&x[(size_t)r * 64 + 8 * i8]);   // self row
      int beg = rowptr[r], end = rowptr[r + 1];
      int c = beg;
      for (; c + 16 <= end; c += 16) {
        int n0 = csr[c + g8];
        int n1 = csr[c + 8 + g8];
        uint4 u0 = *(const uint4*)&x[(size_t)n0 * 64 + 8 * i8];
        uint4 u1 = *(const uint4*)&x[(size_t)n1 * 64 + 8 * i8];
        acc8(a, u0);
        acc8(a, u1);
      }
      if (c + 8 <= end) {
        int n0 = csr[c + g8];
        acc8(a, *(const uint4*)&x[(size_t)n0 * 64 + 8 * i8]);
        c += 8;
      }
      int rem = end - c;
      if (g8 < rem) {
        int n0 = csr[c + g8];
        acc8(a, *(const uint4*)&x[(size_t)n0 * 64 + 8 * i8]);
      }
    }
    // combine across the 8 neighbor slots
#pragma unroll
    for (int k = 0; k < 8; ++k) {
      a[k] += __shfl_xor(a[k], 8, 64);
      a[k] += __shfl_xor(a[k], 16, 64);
      a[k] += __shfl_xor(a[k], 32, 64);
    }
    if (g8 == 0) {
      __half hv[8];
#pragma unroll
      for (int k = 0; k < 8; ++k) hv[k] = __float2half(a[k]);
      *(uint4*)&AsH[lr][8 * i8] = *(uint4*)hv;   // 16B, conflict-free
    }
  }
  __syncthreads();

  v4f acc[4];
#pragma unroll
  for (int t = 0; t < 4; ++t) acc[t] = (v4f){0.f, 0.f, 0.f, 0.f};
#pragma unroll
  for (int hh = 0; hh < 2; ++hh) {
    v8h af = *(const v8h*)&AsH[w * 16 + i][hh * 32 + q * 8];
#pragma unroll
    for (int t = 0; t < 4; ++t) {
      v8h bf = *(const v8h*)&BT[(size_t)(t * 16 + i) * 64 + hh * 32 + q * 8];
      acc[t] = __builtin_amdgcn_mfma_f32_16x16x32_f16(af, bf, acc[t], 0, 0, 0);
    }
  }

  float s[4] = {0.f, 0.f, 0.f, 0.f}, qq[4] = {0.f, 0.f, 0.f, 0.f};
#pragma unroll
  for (int j = 0; j < 4; ++j) {
    int row = rblk + w * 16 + 4 * q + j;
    if (row >= M) continue;
#pragma unroll
    for (int t = 0; t < 4; ++t) {
      float v = h2f(fmaxf(acc[t][j] + bias[i + 16 * t], 0.f));
      h[(size_t)row * 64 + i + 16 * t] = __float2half(v);
      s[t] += v;
      qq[t] += v * v;
    }
  }
  {
    int g = w * 4 + q;                 // 16 row-groups
#pragma unroll
    for (int t = 0; t < 4; ++t) {
      st[g * 64 + i + 16 * t]        = s[t];
      st[1024 + g * 64 + i + 16 * t] = qq[t];
    }
    __syncthreads();
    if (tid < 64) {
      float a = 0.f, b = 0.f;
#pragma unroll
      for (int g2 = 0; g2 < 16; ++g2) {
        a += st[g2 * 64 + tid];
        b += st[1024 + g2 * 64 + tid];
      }
      atomicAdd(&gstat[tid], a);
      atomicAdd(&gstat[64 + tid], b);
    }
  }
}

// ---------------------------------------------------------------------------
// K2 (64-row tile, MFMA, no A/B LDS): xn = relu(BN(h) @ W2 + b2), col63=0;
// fused hyp epilogue. A-frags direct from global (BN applied in registers),
// B-frags direct from global. If Zn != null: write X,Zn; else logmap0+pool.
// ---------------------------------------------------------------------------
__global__ __launch_bounds__(256) void k_layer2(
    const __half* __restrict__ A, const __half* __restrict__ BT,
    const float* __restrict__ bias,
    const float* __restrict__ gstat, const float* __restrict__ gamma,
    const float* __restrict__ beta,
    __half* __restrict__ X,
    const __half* __restrict__ Zc, const __half* Zp, __half* Zn,
    const int* __restrict__ batch, float* __restrict__ pool, int M)
{
  __shared__ float scl_s[64], shf_s[64];
  const int tid  = threadIdx.x;
  const int w    = tid >> 6;
  const int lane = tid & 63;
  const int q    = lane >> 4;
  const int i    = lane & 15;
  const int rblk = blockIdx.x * 64;
  const int arow = rblk + w * 16 + i;

  if (tid < 64) {
    float mu  = gstat[tid] / (float)M;
    float var = gstat[64 + tid] / (float)M - mu * mu;
    float sv  = gamma[tid] / sqrtf(var + BN_EPS_F);
    scl_s[tid] = sv;
    shf_s[tid] = beta[tid] - mu * sv;
  }

  // prefetch zc/zp (per-lane cols i+16t for my 4 C-rows)
  float zcv4[4][4], zpv4[4][4];
#pragma unroll
  for (int j = 0; j < 4; ++j) {
    int row = rblk + w * 16 + 4 * q + j;
    bool valid = (row < M);
#pragma unroll
    for (int t = 0; t < 4; ++t) {
      zcv4[j][t] = valid ? __half2float(Zc[(size_t)row * 64 + i + 16 * t]) : 0.f;
      zpv4[j][t] = (valid && Zp != nullptr)
                     ? __half2float(Zp[(size_t)row * 64 + i + 16 * t]) : 0.f;
    }
  }
  __syncthreads();

  v4f acc[4];
#pragma unroll
  for (int t = 0; t < 4; ++t) acc[t] = (v4f){0.f, 0.f, 0.f, 0.f};
#pragma unroll
  for (int hh = 0; hh < 2; ++hh) {
    const int k0 = hh * 32 + q * 8;
    v8h af = (v8h){0, 0, 0, 0, 0, 0, 0, 0};
    {
      float hv[8] = {0,0,0,0,0,0,0,0};
      if (arow < M) {
        uint4 u = *(const uint4*)&A[(size_t)arow * 64 + k0];
        __half2 h0 = *(__half2*)&u.x;
        __half2 h1 = *(__half2*)&u.y;
        __half2 h2 = *(__half2*)&u.z;
        __half2 h3 = *(__half2*)&u.w;
        hv[0] = __low2float(h0); hv[1] = __high2float(h0);
        hv[2] = __low2float(h1); hv[3] = __high2float(h1);
        hv[4] = __low2float(h2); hv[5] = __high2float(h2);
        hv[6] = __low2float(h3); hv[7] = __high2float(h3);
      }
#pragma unroll
      for (int k = 0; k < 8; ++k)
        af[k] = (_Float16)fmaf(hv[k], scl_s[k0 + k], shf_s[k0 + k]);
    }
#pragma unroll
    for (int t = 0; t < 4; ++t) {
      v8h bf = *(const v8h*)&BT[(size_t)(t * 16 + i) * 64 + k0];
      acc[t] = __builtin_amdgcn_mfma_f32_16x16x32_f16(af, bf, acc[t], 0, 0, 0);
    }
  }

#pragma unroll
  for (int j = 0; j < 4; ++j) {
    int row = rblk + w * 16 + 4 * q + j;
    bool valid = (row < M);
    float xv[4];
#pragma unroll
    for (int t = 0; t < 4; ++t)
      xv[t] = h2f(fmaxf(acc[t][j] + bias[i + 16 * t], 0.f));
    if (i == 15) xv[3] = 0.f;          // col 63
    if (valid && X != nullptr) {
#pragma unroll
      for (int t = 0; t < 4; ++t)
        X[(size_t)row * 64 + i + 16 * t] = __float2half(xv[t]);
    }

    float zcv[4] = {zcv4[j][0], zcv4[j][1], zcv4[j][2], zcv4[j][3]};
    float zpv[4] = {zpv4[j][0], zpv4[j][1], zpv4[j][2], zpv4[j][3]};

    float p1 = xv[0]*xv[0] + xv[1]*xv[1] + xv[2]*xv[2] + xv[3]*xv[3];
    float p2 = zcv[0]*zcv[0]+zcv[1]*zcv[1]+zcv[2]*zcv[2]+zcv[3]*zcv[3];
    float p3 = zpv[0]*zpv[0]+zpv[1]*zpv[1]+zpv[2]*zpv[2]+zpv[3]*zpv[3];
    float p4 = zpv[0]*zcv[0]+zpv[1]*zcv[1]+zpv[2]*zcv[2]+zpv[3]*zcv[3];
    float p5 = zpv[0]*xv[0]+zpv[1]*xv[1]+zpv[2]*xv[2]+zpv[3]*xv[3];
    float p6 = zcv[0]*xv[0]+zcv[1]*xv[1]+zcv[2]*xv[2]+zcv[3]*xv[3];
    rsum16x6(p1, p2, p3, p4, p5, p6);
    float zc63 = __shfl(zcv[3], 15, 16);
    float zp63 = __shfl(zpv[3], 15, 16);

    float nzc2 = fmaxf(p2, MINNORM_F);
    float icz  = 1.0f / nzc2;
    float na2  = p2 * icz * icz;
    float r2   = na2 - 1.0f;
    float a63  = zc63 * icz;

    float sxn = fmaxf(sqrtf(p1), MINNORM_F);
    float sc  = ((sxn > MAXNORM_F) ? (MAXNORM_F / sxn) : 1.0f) * SCALING_F;
    float Sch2   = sc * sc * p1;
    float Szp_a  = p4 * icz;
    float Sa_ch  = sc * p6 * icz;
    float Szp_ch = sc * p5;
    float Su_a   = Szp_a - na2;
    float Su2    = p3 - 2.0f * Szp_a + na2;
    float nu2    = fmaxf(Su2, MINNORM_F);
    float t1     = r2 / nu2;
    float Szp22  = fmaxf(t1*t1*Su2 + 2.0f*t1*Su_a + na2, 0.0f);
    float npn    = fmaxf(sqrtf(Szp22), MINNORM_F);
    float ipn    = 1.0f / npn;
    float zp2_63 = t1 * (zp63 - a63) + a63;
    float Szp2ch = t1 * (Szp_ch - Sa_ch) + Sa_ch;
    float rdc    = -ipn * Szp2ch;
    float rdr    = 1.0f - 2.0f*ipn*zp2_63 + ipn*ipn*Szp22;
    float m2     = 2.0f * rdc / rdr;
    float Szp2a  = t1 * Su_a + na2;
    float Srr_a  = a63 - ipn * Szp2a;
    float Sc2a   = Sa_ch - m2 * Srr_a;
    float Sc22   = Sch2 - 2.0f*m2*rdc + m2*m2*rdr;
    float Sc2ma  = Sc22 - 2.0f*Sc2a + na2;
    float nu22   = fmaxf(Sc2ma, MINNORM_F);
    float t2     = r2 / nu22;

    float zn[4];
#pragma unroll
    for (int t = 0; t < 4; ++t) {
      float ai  = zcv[t] * icz;
      float zp2 = t1 * (zpv[t] - ai) + ai;
      float rri = ((i == 15 && t == 3) ? 1.0f : 0.0f) - ipn * zp2;
      float c2  = sc * xv[t] - m2 * rri;
      zn[t]     = t2 * (c2 - ai) + ai;
    }

    if (Zn != nullptr) {
      if (valid) {
#pragma unroll
        for (int t = 0; t < 4; ++t)
          Zn[(size_t)row * 64 + i + 16 * t] = __float2half(zn[t]);
      }
    } else {
      float Szn2 = fmaxf(t2*t2*Sc2ma + 2.0f*t2*(Sc2a - na2) + na2, 0.0f);
      float yn  = fmaxf(sqrtf(Szn2), MINNORM_F);
      float t   = fminf(yn, 1.0f);
      float ath = 0.5f * logf((1.0f + t) / (1.0f - t));
      float wsc = ath / yn;
      if (valid) {
        int b = batch[row];
        float* p = &pool[(size_t)b * 64 + i];
#pragma unroll
        for (int t4 = 0; t4 < 4; ++t4)
          atomicAdd(p + 16 * t4, zn[t4] * wsc);
      }
    }
  }
}

// ---------------------------------------------------------------------------
// CSR build
// ---------------------------------------------------------------------------
__global__ __launch_bounds__(256) void k_deg(const int* __restrict__ dst, int E, int* deg) {
  int i0 = (blockIdx.x * 256 + threadIdx.x) * 4;
  if (i0 + 4 <= E) {
    int d0 = dst[i0], d1 = dst[i0+1], d2 = dst[i0+2], d3 = dst[i0+3];
    atomicAdd(&deg[d0], 1);
    atomicAdd(&deg[d1], 1);
    atomicAdd(&deg[d2], 1);
    atomicAdd(&deg[d3], 1);
  } else {
    for (int i = i0; i < E; ++i) atomicAdd(&deg[dst[i]], 1);
  }
}

__global__ __launch_bounds__(256) void k_scan1(const int* __restrict__ deg, int N,
                                               int* rowptr, int* bsum) {
  __shared__ int s[256];
  int t = threadIdx.x;
  int i = blockIdx.x * 256 + t;
  int v = (i < N) ? deg[i] : 0;
  s[t] = v;
  __syncthreads();
  for (int d = 1; d < 256; d <<= 1) {
    int add = (t >= d) ? s[t - d] : 0;
    __syncthreads();
    s[t] += add;
    __syncthreads();
  }
  if (i < N) rowptr[i] = s[t] - v;
  if (t == 255) bsum[blockIdx.x] = s[255];
}

__global__ __launch_bounds__(256) void k_scan2(const int* __restrict__ bsum, int NB, int* boff) {
  __shared__ int s[256];
  int t = threadIdx.x;
  int v = (t < NB) ? bsum[t] : 0;
  s[t] = v;
  __syncthreads();
  for (int d = 1; d < 256; d <<= 1) {
    int add = (t >= d) ? s[t - d] : 0;
    __syncthreads();
    s[t] += add;
    __syncthreads();
  }
  boff[t] = s[t] - v;
}

__global__ __launch_bounds__(256) void k_scan3(int* rowptr, const int* __restrict__ boff,
                                               int* cursor, int N, int E) {
  int i = blockIdx.x * 256 + threadIdx.x;
  if (i < N) {
    int v = rowptr[i] + boff[blockIdx.x];
    rowptr[i] = v;
    cursor[i] = v;
  }
  if (i == 0) rowptr[N] = E;
}

__global__ __launch_bounds__(256) void k_fill(const int* __restrict__ src,
                                              const int* __restrict__ dst, int E,
                                              int* cursor, int* __restrict__ csr) {
  int i0 = (blockIdx.x * 256 + threadIdx.x) * 4;
  if (i0 + 4 <= E) {
    int d0 = dst[i0], d1 = dst[i0+1], d2 = dst[i0+2], d3 = dst[i0+3];
    int s0 = src[i0], s1 = src[i0+1], s2 = src[i0+2], s3 = src[i0+3];
    int p0 = atomicAdd(&cursor[d0], 1);
    int p1 = atomicAdd(&cursor[d1], 1);
    int p2 = atomicAdd(&cursor[d2], 1);
    int p3 = atomicAdd(&cursor[d3], 1);
    csr[p0] = s0;
    csr[p1] = s1;
    csr[p2] = s2;
    csr[p3] = s3;
  } else {
    for (int i = i0; i < E; ++i) {
      int p = atomicAdd(&cursor[dst[i]], 1);
      csr[p] = src[i];
    }
  }
}

// ---------------------------------------------------------------------------
// Per-graph MLP head + log_softmax
// ---------------------------------------------------------------------------
__global__ __launch_bounds__(128) void k_mlp(const float* __restrict__ pool,
                                             const float* __restrict__ fc1W, const float* __restrict__ fc1b,
                                             const float* __restrict__ fc2W, const float* __restrict__ fc2b,
                                             const float* __restrict__ fc3W, const float* __restrict__ fc3b,
                                             float* __restrict__ out) {
  __shared__ float p[64], o1[128], o2[64], lg[10], red[2];
  int g = blockIdx.x, t = threadIdx.x;
  if (t < 64) p[t] = pool[(size_t)g * 64 + t];
  __syncthreads();
  {
    float a = fc1b[t];
    for (int k = 0; k < 64; ++k) a = fmaf(p[k], fc1W[k * 128 + t], a);
    o1[t] = fmaxf(a, 0.f);
  }
  __syncthreads();
  if (t < 64) {
    float a = fc2b[t];
    for (int k = 0; k < 128; ++k) a = fmaf(o1[k], fc2W[k * 64 + t], a);
    o2[t] = fmaxf(a, 0.f);
  }
  __syncthreads();
  if (t < 10) {
    float a = fc3b[t];
    for (int k = 0; k < 64; ++k) a = fmaf(o2[k], fc3W[k * 10 + t], a);
    lg[t] = a;
  }
  __syncthreads();
  if (t == 0) {
    float mx = lg[0];
    for (int j = 1; j < 10; ++j) mx = fmaxf(mx, lg[j]);
    float s = 0.f;
    for (int j = 0; j < 10; ++j) s += expf(lg[j] - mx);
    red[0] = mx;
    red[1] = logf(s);
  }
  __syncthreads();
  if (t < 10) out[(size_t)g * 10 + t] = lg[t] - red[0] - red[1];
}

// ---------------------------------------------------------------------------
extern "C" void kernel_launch(void* const* d_in, const int* in_sizes, int n_in,
                              void* d_out, int out_size, void* d_ws, size_t ws_size,
                              hipStream_t stream) {
  const float* x_in  = (const float*)d_in[0];
  const int*   ei    = (const int*)d_in[1];
  const int*   batch = (const int*)d_in[2];
  const float* W0    = (const float*)d_in[3];
  const float* b0    = (const float*)d_in[4];
  const float* cW1   = (const float*)d_in[5];
  const float* cb1   = (const float*)d_in[6];
  const float* gamma = (const float*)d_in[7];
  const float* beta  = (const float*)d_in[8];
  const float* cW2   = (const float*)d_in[9];
  const float* cb2   = (const float*)d_in[10];
  const float* fc1W  = (const float*)d_in[11];
  const float* fc1b  = (const float*)d_in[12];
  const float* fc2W  = (const float*)d_in[13];
  const float* fc2b  = (const float*)d_in[14];
  const float* fc3W  = (const float*)d_in[15];
  const float* fc3b  = (const float*)d_in[16];
  float* out = (float*)d_out;

  const int N = in_sizes[0] / 128;
  const int E = in_sizes[1] / 2;
  const int L = in_sizes[5] / (64 * 64);
  const int G = out_size / 10;
  const int* src = ei;
  const int* dst = ei + E;

  char* ws = (char*)d_ws;
  size_t off = 0;
  auto alloc = [&](size_t bytes) -> char* {
    char* p = ws + off;
    off += (bytes + 255) & ~(size_t)255;
    return p;
  };
  __half* X   = (__half*)alloc((size_t)N * 64 * 2);
  __half* Bf  = (__half*)alloc((size_t)N * 64 * 2);
  __half* zb0 = (__half*)alloc((size_t)N * 64 * 2);
  __half* zb1 = (__half*)alloc((size_t)N * 64 * 2);
  __half* zb2 = (__half*)alloc((size_t)N * 64 * 2);
  __half* W0T = (__half*)alloc((size_t)64 * 128 * 2);
  __half* W1T = (__half*)alloc((size_t)L * 64 * 64 * 2);
  __half* W2T = (__half*)alloc((size_t)L * 64 * 64 * 2);
  // ---- zeroed region: deg, pool, gstatAll (contiguous) ----
  int*   deg  = (int*)alloc((size_t)N * 4);
  float* pool = (float*)alloc((size_t)G * 64 * 4);
  float* gstatAll = (float*)alloc((size_t)3 * 128 * 4);
  char*  zero_end = ws + off;
  // ---------------------------------------------------------
  int*   rowptr = (int*)alloc((size_t)(N + 1) * 4);
  int*   cursor = (int*)alloc((size_t)N * 4);
  int*   csr    = (int*)alloc((size_t)E * 4);
  int*   bsum   = (int*)alloc(256 * 4);
  int*   boff   = (int*)alloc(256 * 4);
  __half* zbuf[3] = {zb0, zb1, zb2};

  hipMemsetAsync(deg, 0, (size_t)(zero_end - (char*)deg), stream);

  const int mmGrid    = (N + 63) / 64;
  const int edge4Grid = (E / 4 + 255) / 256 + 1;
  const int wcvtGrid  = (((L * 4096 > 8192) ? L * 4096 : 8192) + 255) / 256;

  // one-time weight conversion to fp16 transposed
  k_wcvt<<<wcvtGrid, 256, 0, stream>>>(W0, cW1, cW2, L, W0T, W1T, W2T);

  // X = relu(x @ W0 + b0) (fp16); Z1 = SCALING*project(X) (fp16)
  k_mm0<<<mmGrid, 256, 0, stream>>>(x_in, W0T, b0, X, zbuf[0], N);

  // CSR build
  k_deg<<<edge4Grid, 256, 0, stream>>>(dst, E, deg);
  const int NB = (N + 255) / 256;
  k_scan1<<<NB, 256, 0, stream>>>(deg, N, rowptr, bsum);
  k_scan2<<<1, 256, 0, stream>>>(bsum, NB, boff);
  k_scan3<<<NB, 256, 0, stream>>>(rowptr, boff, cursor, N, E);
  k_fill<<<edge4Grid, 256, 0, stream>>>(src, dst, E, cursor, csr);

  for (int i = 0; i < L; ++i) {
    float* gstat = gstatAll + (size_t)i * 128;
    const int last = (i == L - 1);
    k_layer1<<<mmGrid, 256, 0, stream>>>(X, rowptr, csr,
                                         W1T + (size_t)i * 4096, cb1 + i * 64,
                                         Bf, gstat, N);
    k_layer2<<<mmGrid, 256, 0, stream>>>(Bf, W2T + (size_t)i * 4096, cb2 + i * 64,
                                         gstat, gamma + i * 64, beta + i * 64,
                                         last ? nullptr : X,
                                         zbuf[i],
                                         (i == 0) ? nullptr : zbuf[i - 1],
                                         last ? nullptr : zbuf[i + 1],
                                         batch, pool, N);
  }

  k_mlp<<<G, 128, 0, stream>>>(pool, fc1W, fc1b, fc2W, fc2b, fc3W, fc3b, out);
}

// Round 12
// 464.366 us; speedup vs baseline: 1.1303x; 1.0283x over previous
//
#include <hip/hip_runtime.h>
#include <hip/hip_fp16.h>
#include <math.h>

#define SCALING_F 0.46211715726000974f   // tanh(0.5)
#define MAXNORM_F 0.996f                 // 1 - BALL_EPS
#define MINNORM_F 1e-15f
#define BN_EPS_F  1e-5f

typedef _Float16 v8h __attribute__((ext_vector_type(8)));
typedef float    v4f __attribute__((ext_vector_type(4)));

// reduce over the 16-lane group holding one row
__device__ __forceinline__ float rsum16(float v) {
  v += __shfl_xor(v, 1, 64);
  v += __shfl_xor(v, 2, 64);
  v += __shfl_xor(v, 4, 64);
  v += __shfl_xor(v, 8, 64);
  return v;
}

__device__ __forceinline__ void rsum16x6(float& a, float& b, float& c,
                                         float& d, float& e, float& f) {
#pragma unroll
  for (int o = 1; o <= 8; o <<= 1) {
    a += __shfl_xor(a, o, 64);
    b += __shfl_xor(b, o, 64);
    c += __shfl_xor(c, o, 64);
    d += __shfl_xor(d, o, 64);
    e += __shfl_xor(e, o, 64);
    f += __shfl_xor(f, o, 64);
  }
}

__device__ __forceinline__ float h2f(float v) {   // fp16 round-trip
  return __half2float(__float2half(v));
}

// accumulate 8 halfs (as uint4) into float[8]
__device__ __forceinline__ void acc8(float* a, uint4 u) {
  __half2 h0 = *(__half2*)&u.x;
  __half2 h1 = *(__half2*)&u.y;
  __half2 h2 = *(__half2*)&u.z;
  __half2 h3 = *(__half2*)&u.w;
  a[0] += __low2float(h0); a[1] += __high2float(h0);
  a[2] += __low2float(h1); a[3] += __high2float(h1);
  a[4] += __low2float(h2); a[5] += __high2float(h2);
  a[6] += __low2float(h3); a[7] += __high2float(h3);
}

// ---------------------------------------------------------------------------
// One-time weight conversion: fp32 row-major [K][64] -> fp16 transposed [n][k]
// ---------------------------------------------------------------------------
__global__ __launch_bounds__(256) void k_wcvt(
    const float* __restrict__ W0, const float* __restrict__ cW1,
    const float* __restrict__ cW2, int L,
    __half* __restrict__ W0T, __half* __restrict__ W1T, __half* __restrict__ W2T)
{
  int id = blockIdx.x * 256 + threadIdx.x;
  if (id < 64 * 128) {            // W0T[n][k], k<128
    int n = id >> 7, k = id & 127;
    W0T[id] = __float2half(W0[(size_t)k * 64 + n]);
  }
  if (id < L * 64 * 64) {         // W1T/W2T[l][n][k]
    int l = id >> 12, rem = id & 4095;
    int n = rem >> 6, k = rem & 63;
    W1T[id] = __float2half(cW1[(size_t)l * 4096 + k * 64 + n]);
    W2T[id] = __float2half(cW2[(size_t)l * 4096 + k * 64 + n]);
  }
}

// ---------------------------------------------------------------------------
// mm0 (64-row tile, MFMA, no LDS): X = relu(x_in @ W0 + b0) (K=128, fp16 X),
// fused proj: Z[row] = SCALING * project(X[row])  (fp16)
// ---------------------------------------------------------------------------
__global__ __launch_bounds__(256) void k_mm0(
    const float* __restrict__ A, const __half* __restrict__ BT,
    const float* __restrict__ bias, __half* __restrict__ X,
    __half* __restrict__ Z, int M)
{
  const int tid  = threadIdx.x;
  const int w    = tid >> 6;
  const int lane = tid & 63;
  const int q    = lane >> 4;
  const int i    = lane & 15;
  const int rblk = blockIdx.x * 64;
  const int arow = rblk + w * 16 + i;     // A-operand row for this lane

  v4f acc[4];
#pragma unroll
  for (int t = 0; t < 4; ++t) acc[t] = (v4f){0.f, 0.f, 0.f, 0.f};

#pragma unroll
  for (int hh = 0; hh < 4; ++hh) {
    v8h af = (v8h){0, 0, 0, 0, 0, 0, 0, 0};
    if (arow < M) {
      const float* p = &A[(size_t)arow * 128 + hh * 32 + q * 8];
      float4 fa = *(const float4*)p;
      float4 fb = *(const float4*)(p + 4);
      af[0] = (_Float16)fa.x; af[1] = (_Float16)fa.y;
      af[2] = (_Float16)fa.z; af[3] = (_Float16)fa.w;
      af[4] = (_Float16)fb.x; af[5] = (_Float16)fb.y;
      af[6] = (_Float16)fb.z; af[7] = (_Float16)fb.w;
    }
#pragma unroll
    for (int t = 0; t < 4; ++t) {
      v8h bf = *(const v8h*)&BT[(size_t)(t * 16 + i) * 128 + hh * 32 + q * 8];
      acc[t] = __builtin_amdgcn_mfma_f32_16x16x32_f16(af, bf, acc[t], 0, 0, 0);
    }
  }

#pragma unroll
  for (int j = 0; j < 4; ++j) {
    int row = rblk + w * 16 + 4 * q + j;
    bool valid = (row < M);
    float xv[4];
#pragma unroll
    for (int t = 0; t < 4; ++t)
      xv[t] = h2f(fmaxf(acc[t][j] + bias[i + 16 * t], 0.f));
    if (valid) {
#pragma unroll
      for (int t = 0; t < 4; ++t)
        X[(size_t)row * 64 + i + 16 * t] = __float2half(xv[t]);
    }
    float sx = rsum16(xv[0]*xv[0] + xv[1]*xv[1] + xv[2]*xv[2] + xv[3]*xv[3]);
    float norm = fmaxf(sqrtf(sx), MINNORM_F);
    float s = ((norm > MAXNORM_F) ? (MAXNORM_F / norm) : 1.0f) * SCALING_F;
    if (valid) {
#pragma unroll
      for (int t = 0; t < 4; ++t)
        Z[(size_t)row * 64 + i + 16 * t] = __float2half(xv[t] * s);
    }
  }
}

// ---------------------------------------------------------------------------
// K1 (64-row tile, MFMA): h = relu((x[r] + sum_nb x[nb]) @ W1 + b1).
// Gather: 8 neighbors per wave-load, TWO rows interleaved per iteration
// (two independent csr streams -> 2-4 gather loads in flight per wave).
// ---------------------------------------------------------------------------
__global__ __launch_bounds__(256, 6) void k_layer1(
    const __half* __restrict__ x, const int* __restrict__ rowptr,
    const int* __restrict__ csr, const __half* __restrict__ BT,
    const float* __restrict__ bias, __half* __restrict__ h,
    float* __restrict__ gstat, int M)
{
  __shared__ __half AsH[64][80];   // 160B rows (16B aligned)
  __shared__ float st[2048];
  const int tid  = threadIdx.x;
  const int w    = tid >> 6;
  const int lane = tid & 63;
  const int q    = lane >> 4;
  const int i    = lane & 15;
  const int g8   = lane >> 3;      // neighbor slot 0..7
  const int i8   = lane & 7;       // col group: cols 8*i8 .. +8
  const int rblk = blockIdx.x * 64;

  // gather-stage A: one wave per 16 rows; 2 rows interleaved per iteration
  for (int pr = 0; pr < 8; ++pr) {
    int lr0 = w * 16 + 2 * pr;
    int lr1 = lr0 + 1;
    int r0 = rblk + lr0, r1 = rblk + lr1;
    bool v0 = (r0 < M), v1 = (r1 < M);
    float a0[8] = {0.f,0.f,0.f,0.f,0.f,0.f,0.f,0.f};
    float a1[8] = {0.f,0.f,0.f,0.f,0.f,0.f,0.f,0.f};
    int c0 = 0, e0 = 0, c1 = 0, e1 = 0;
    if (v0) { c0 = rowptr[r0]; e0 = rowptr[r0 + 1]; }
    if (v1) { c1 = rowptr[r1]; e1 = rowptr[r1 + 1]; }
    // self rows (two independent predicated loads)
    if (v0 && g8 == 0) acc8(a0, *(const uint4*)&x[(size_t)r0 * 64 + 8 * i8]);
    if (v1 && g8 == 0) acc8(a1, *(const uint4*)&x[(size_t)r1 * 64 + 8 * i8]);

    // fast path: both streams have >=16 edges -> 4 gathers in flight
    while (c0 + 16 <= e0 && c1 + 16 <= e1) {
      int n0a = csr[c0 + g8];
      int n0b = csr[c0 + 8 + g8];
      int n1a = csr[c1 + g8];
      int n1b = csr[c1 + 8 + g8];
      uint4 u0a = *(const uint4*)&x[(size_t)n0a * 64 + 8 * i8];
      uint4 u0b = *(const uint4*)&x[(size_t)n0b * 64 + 8 * i8];
      uint4 u1a = *(const uint4*)&x[(size_t)n1a * 64 + 8 * i8];
      uint4 u1b = *(const uint4*)&x[(size_t)n1b * 64 + 8 * i8];
      acc8(a0, u0a);
      acc8(a0, u0b);
      acc8(a1, u1a);
      acc8(a1, u1b);
      c0 += 16;
      c1 += 16;
    }
    // mixed path: whichever stream still has >=8
    while (c0 + 8 <= e0 || c1 + 8 <= e1) {
      bool d0 = (c0 + 8 <= e0);
      bool d1 = (c1 + 8 <= e1);
      int n0 = 0, n1 = 0;
      if (d0) n0 = csr[c0 + g8];
      if (d1) n1 = csr[c1 + g8];
      uint4 u0, u1;
      if (d0) u0 = *(const uint4*)&x[(size_t)n0 * 64 + 8 * i8];
      if (d1) u1 = *(const uint4*)&x[(size_t)n1 * 64 + 8 * i8];
      if (d0) { acc8(a0, u0); c0 += 8; }
      if (d1) { acc8(a1, u1); c1 += 8; }
    }
    // remainders (per-lane predicated, both independent)
    {
      int rem0 = e0 - c0;
      int rem1 = e1 - c1;
      int n0 = 0, n1 = 0;
      if (g8 < rem0) n0 = csr[c0 + g8];
      if (g8 < rem1) n1 = csr[c1 + g8];
      uint4 u0, u1;
      if (g8 < rem0) u0 = *(const uint4*)&x[(size_t)n0 * 64 + 8 * i8];
      if (g8 < rem1) u1 = *(const uint4*)&x[(size_t)n1 * 64 + 8 * i8];
      if (g8 < rem0) acc8(a0, u0);
      if (g8 < rem1) acc8(a1, u1);
    }
    // combine across the 8 neighbor slots (both rows interleaved)
#pragma unroll
    for (int k = 0; k < 8; ++k) {
      a0[k] += __shfl_xor(a0[k], 8, 64);
      a1[k] += __shfl_xor(a1[k], 8, 64);
      a0[k] += __shfl_xor(a0[k], 16, 64);
      a1[k] += __shfl_xor(a1[k], 16, 64);
      a0[k] += __shfl_xor(a0[k], 32, 64);
      a1[k] += __shfl_xor(a1[k], 32, 64);
    }
    if (g8 == 0) {
      __half hv0[8], hv1[8];
#pragma unroll
      for (int k = 0; k < 8; ++k) { hv0[k] = __float2half(a0[k]); hv1[k] = __float2half(a1[k]); }
      *(uint4*)&AsH[lr0][8 * i8] = *(uint4*)hv0;   // 16B, conflict-free
      *(uint4*)&AsH[lr1][8 * i8] = *(uint4*)hv1;
    }
  }
  __syncthreads();

  v4f acc[4];
#pragma unroll
  for (int t = 0; t < 4; ++t) acc[t] = (v4f){0.f, 0.f, 0.f, 0.f};
#pragma unroll
  for (int hh = 0; hh < 2; ++hh) {
    v8h af = *(const v8h*)&AsH[w * 16 + i][hh * 32 + q * 8];
#pragma unroll
    for (int t = 0; t < 4; ++t) {
      v8h bf = *(const v8h*)&BT[(size_t)(t * 16 + i) * 64 + hh * 32 + q * 8];
      acc[t] = __builtin_amdgcn_mfma_f32_16x16x32_f16(af, bf, acc[t], 0, 0, 0);
    }
  }

  float s[4] = {0.f, 0.f, 0.f, 0.f}, qq[4] = {0.f, 0.f, 0.f, 0.f};
#pragma unroll
  for (int j = 0; j < 4; ++j) {
    int row = rblk + w * 16 + 4 * q + j;
    if (row >= M) continue;
#pragma unroll
    for (int t = 0; t < 4; ++t) {
      float v = h2f(fmaxf(acc[t][j] + bias[i + 16 * t], 0.f));
      h[(size_t)row * 64 + i + 16 * t] = __float2half(v);
      s[t] += v;
      qq[t] += v * v;
    }
  }
  {
    int g = w * 4 + q;                 // 16 row-groups
#pragma unroll
    for (int t = 0; t < 4; ++t) {
      st[g * 64 + i + 16 * t]        = s[t];
      st[1024 + g * 64 + i + 16 * t] = qq[t];
    }
    __syncthreads();
    if (tid < 64) {
      float a = 0.f, b = 0.f;
#pragma unroll
      for (int g2 = 0; g2 < 16; ++g2) {
        a += st[g2 * 64 + tid];
        b += st[1024 + g2 * 64 + tid];
      }
      atomicAdd(&gstat[tid], a);
      atomicAdd(&gstat[64 + tid], b);
    }
  }
}

// ---------------------------------------------------------------------------
// K2 (64-row tile, MFMA, no A/B LDS): xn = relu(BN(h) @ W2 + b2), col63=0;
// fused hyp epilogue. A-frags direct from global (BN applied in registers),
// B-frags direct from global. If Zn != null: write X,Zn; else logmap0+pool.
// ---------------------------------------------------------------------------
__global__ __launch_bounds__(256) void k_layer2(
    const __half* __restrict__ A, const __half* __restrict__ BT,
    const float* __restrict__ bias,
    const float* __restrict__ gstat, const float* __restrict__ gamma,
    const float* __restrict__ beta,
    __half* __restrict__ X,
    const __half* __restrict__ Zc, const __half* Zp, __half* Zn,
    const int* __restrict__ batch, float* __restrict__ pool, int M)
{
  __shared__ float scl_s[64], shf_s[64];
  const int tid  = threadIdx.x;
  const int w    = tid >> 6;
  const int lane = tid & 63;
  const int q    = lane >> 4;
  const int i    = lane & 15;
  const int rblk = blockIdx.x * 64;
  const int arow = rblk + w * 16 + i;

  if (tid < 64) {
    float mu  = gstat[tid] / (float)M;
    float var = gstat[64 + tid] / (float)M - mu * mu;
    float sv  = gamma[tid] / sqrtf(var + BN_EPS_F);
    scl_s[tid] = sv;
    shf_s[tid] = beta[tid] - mu * sv;
  }

  // prefetch zc/zp (per-lane cols i+16t for my 4 C-rows)
  float zcv4[4][4], zpv4[4][4];
#pragma unroll
  for (int j = 0; j < 4; ++j) {
    int row = rblk + w * 16 + 4 * q + j;
    bool valid = (row < M);
#pragma unroll
    for (int t = 0; t < 4; ++t) {
      zcv4[j][t] = valid ? __half2float(Zc[(size_t)row * 64 + i + 16 * t]) : 0.f;
      zpv4[j][t] = (valid && Zp != nullptr)
                     ? __half2float(Zp[(size_t)row * 64 + i + 16 * t]) : 0.f;
    }
  }
  __syncthreads();

  v4f acc[4];
#pragma unroll
  for (int t = 0; t < 4; ++t) acc[t] = (v4f){0.f, 0.f, 0.f, 0.f};
#pragma unroll
  for (int hh = 0; hh < 2; ++hh) {
    const int k0 = hh * 32 + q * 8;
    v8h af = (v8h){0, 0, 0, 0, 0, 0, 0, 0};
    {
      float hv[8] = {0,0,0,0,0,0,0,0};
      if (arow < M) {
        uint4 u = *(const uint4*)&A[(size_t)arow * 64 + k0];
        __half2 h0 = *(__half2*)&u.x;
        __half2 h1 = *(__half2*)&u.y;
        __half2 h2 = *(__half2*)&u.z;
        __half2 h3 = *(__half2*)&u.w;
        hv[0] = __low2float(h0); hv[1] = __high2float(h0);
        hv[2] = __low2float(h1); hv[3] = __high2float(h1);
        hv[4] = __low2float(h2); hv[5] = __high2float(h2);
        hv[6] = __low2float(h3); hv[7] = __high2float(h3);
      }
#pragma unroll
      for (int k = 0; k < 8; ++k)
        af[k] = (_Float16)fmaf(hv[k], scl_s[k0 + k], shf_s[k0 + k]);
    }
#pragma unroll
    for (int t = 0; t < 4; ++t) {
      v8h bf = *(const v8h*)&BT[(size_t)(t * 16 + i) * 64 + k0];
      acc[t] = __builtin_amdgcn_mfma_f32_16x16x32_f16(af, bf, acc[t], 0, 0, 0);
    }
  }

#pragma unroll
  for (int j = 0; j < 4; ++j) {
    int row = rblk + w * 16 + 4 * q + j;
    bool valid = (row < M);
    float xv[4];
#pragma unroll
    for (int t = 0; t < 4; ++t)
      xv[t] = h2f(fmaxf(acc[t][j] + bias[i + 16 * t], 0.f));
    if (i == 15) xv[3] = 0.f;          // col 63
    if (valid && X != nullptr) {
#pragma unroll
      for (int t = 0; t < 4; ++t)
        X[(size_t)row * 64 + i + 16 * t] = __float2half(xv[t]);
    }

    float zcv[4] = {zcv4[j][0], zcv4[j][1], zcv4[j][2], zcv4[j][3]};
    float zpv[4] = {zpv4[j][0], zpv4[j][1], zpv4[j][2], zpv4[j][3]};

    float p1 = xv[0]*xv[0] + xv[1]*xv[1] + xv[2]*xv[2] + xv[3]*xv[3];
    float p2 = zcv[0]*zcv[0]+zcv[1]*zcv[1]+zcv[2]*zcv[2]+zcv[3]*zcv[3];
    float p3 = zpv[0]*zpv[0]+zpv[1]*zpv[1]+zpv[2]*zpv[2]+zpv[3]*zpv[3];
    float p4 = zpv[0]*zcv[0]+zpv[1]*zcv[1]+zpv[2]*zcv[2]+zpv[3]*zcv[3];
    float p5 = zpv[0]*xv[0]+zpv[1]*xv[1]+zpv[2]*xv[2]+zpv[3]*xv[3];
    float p6 = zcv[0]*xv[0]+zcv[1]*xv[1]+zcv[2]*xv[2]+zcv[3]*xv[3];
    rsum16x6(p1, p2, p3, p4, p5, p6);
    float zc63 = __shfl(zcv[3], 15, 16);
    float zp63 = __shfl(zpv[3], 15, 16);

    float nzc2 = fmaxf(p2, MINNORM_F);
    float icz  = 1.0f / nzc2;
    float na2  = p2 * icz * icz;
    float r2   = na2 - 1.0f;
    float a63  = zc63 * icz;

    float sxn = fmaxf(sqrtf(p1), MINNORM_F);
    float sc  = ((sxn > MAXNORM_F) ? (MAXNORM_F / sxn) : 1.0f) * SCALING_F;
    float Sch2   = sc * sc * p1;
    float Szp_a  = p4 * icz;
    float Sa_ch  = sc * p6 * icz;
    float Szp_ch = sc * p5;
    float Su_a   = Szp_a - na2;
    float Su2    = p3 - 2.0f * Szp_a + na2;
    float nu2    = fmaxf(Su2, MINNORM_F);
    float t1     = r2 / nu2;
    float Szp22  = fmaxf(t1*t1*Su2 + 2.0f*t1*Su_a + na2, 0.0f);
    float npn    = fmaxf(sqrtf(Szp22), MINNORM_F);
    float ipn    = 1.0f / npn;
    float zp2_63 = t1 * (zp63 - a63) + a63;
    float Szp2ch = t1 * (Szp_ch - Sa_ch) + Sa_ch;
    float rdc    = -ipn * Szp2ch;
    float rdr    = 1.0f - 2.0f*ipn*zp2_63 + ipn*ipn*Szp22;
    float m2     = 2.0f * rdc / rdr;
    float Szp2a  = t1 * Su_a + na2;
    float Srr_a  = a63 - ipn * Szp2a;
    float Sc2a   = Sa_ch - m2 * Srr_a;
    float Sc22   = Sch2 - 2.0f*m2*rdc + m2*m2*rdr;
    float Sc2ma  = Sc22 - 2.0f*Sc2a + na2;
    float nu22   = fmaxf(Sc2ma, MINNORM_F);
    float t2     = r2 / nu22;

    float zn[4];
#pragma unroll
    for (int t = 0; t < 4; ++t) {
      float ai  = zcv[t] * icz;
      float zp2 = t1 * (zpv[t] - ai) + ai;
      float rri = ((i == 15 && t == 3) ? 1.0f : 0.0f) - ipn * zp2;
      float c2  = sc * xv[t] - m2 * rri;
      zn[t]     = t2 * (c2 - ai) + ai;
    }

    if (Zn != nullptr) {
      if (valid) {
#pragma unroll
        for (int t = 0; t < 4; ++t)
          Zn[(size_t)row * 64 + i + 16 * t] = __float2half(zn[t]);
      }
    } else {
      float Szn2 = fmaxf(t2*t2*Sc2ma + 2.0f*t2*(Sc2a - na2) + na2, 0.0f);
      float yn  = fmaxf(sqrtf(Szn2), MINNORM_F);
      float t   = fminf(yn, 1.0f);
      float ath = 0.5f * logf((1.0f + t) / (1.0f - t));
      float wsc = ath / yn;
      if (valid) {
        int b = batch[row];
        float* p = &pool[(size_t)b * 64 + i];
#pragma unroll
        for (int t4 = 0; t4 < 4; ++t4)
          atomicAdd(p + 16 * t4, zn[t4] * wsc);
      }
    }
  }
}

// ---------------------------------------------------------------------------
// CSR build
// ---------------------------------------------------------------------------
__global__ __launch_bounds__(256) void k_deg(const int* __restrict__ dst, int E, int* deg) {
  int i0 = (blockIdx.x * 256 + threadIdx.x) * 4;
  if (i0 + 4 <= E) {
    int d0 = dst[i0], d1 = dst[i0+1], d2 = dst[i0+2], d3 = dst[i0+3];
    atomicAdd(&deg[d0], 1);
    atomicAdd(&deg[d1], 1);
    atomicAdd(&deg[d2], 1);
    atomicAdd(&deg[d3], 1);
  } else {
    for (int i = i0; i < E; ++i) atomicAdd(&deg[dst[i]], 1);
  }
}

__global__ __launch_bounds__(256) void k_scan1(const int* __restrict__ deg, int N,
                                               int* rowptr, int* bsum) {
  __shared__ int s[256];
  int t = threadIdx.x;
  int i = blockIdx.x * 256 + t;
  int v = (i < N) ? deg[i] : 0;
  s[t] = v;
  __syncthreads();
  for (int d = 1; d < 256; d <<= 1) {
    int add = (t >= d) ? s[t - d] : 0;
    __syncthreads();
    s[t] += add;
    __syncthreads();
  }
  if (i < N) rowptr[i] = s[t] - v;
  if (t == 255) bsum[blockIdx.x] = s[255];
}

__global__ __launch_bounds__(256) void k_scan2(const int* __restrict__ bsum, int NB, int* boff) {
  __shared__ int s[256];
  int t = threadIdx.x;
  int v = (t < NB) ? bsum[t] : 0;
  s[t] = v;
  __syncthreads();
  for (int d = 1; d < 256; d <<= 1) {
    int add = (t >= d) ? s[t - d] : 0;
    __syncthreads();
    s[t] += add;
    __syncthreads();
  }
  boff[t] = s[t] - v;
}

__global__ __launch_bounds__(256) void k_scan3(int* rowptr, const int* __restrict__ boff,
                                               int* cursor, int N, int E) {
  int i = blockIdx.x * 256 + threadIdx.x;
  if (i < N) {
    int v = rowptr[i] + boff[blockIdx.x];
    rowptr[i] = v;
    cursor[i] = v;
  }
  if (i == 0) rowptr[N] = E;
}

__global__ __launch_bounds__(256) void k_fill(const int* __restrict__ src,
                                              const int* __restrict__ dst, int E,
                                              int* cursor, int* __restrict__ csr) {
  int i0 = (blockIdx.x * 256 + threadIdx.x) * 4;
  if (i0 + 4 <= E) {
    int d0 = dst[i0], d1 = dst[i0+1], d2 = dst[i0+2], d3 = dst[i0+3];
    int s0 = src[i0], s1 = src[i0+1], s2 = src[i0+2], s3 = src[i0+3];
    int p0 = atomicAdd(&cursor[d0], 1);
    int p1 = atomicAdd(&cursor[d1], 1);
    int p2 = atomicAdd(&cursor[d2], 1);
    int p3 = atomicAdd(&cursor[d3], 1);
    csr[p0] = s0;
    csr[p1] = s1;
    csr[p2] = s2;
    csr[p3] = s3;
  } else {
    for (int i = i0; i < E; ++i) {
      int p = atomicAdd(&cursor[dst[i]], 1);
      csr[p] = src[i];
    }
  }
}

// ---------------------------------------------------------------------------
// Per-graph MLP head + log_softmax
// ---------------------------------------------------------------------------
__global__ __launch_bounds__(128) void k_mlp(const float* __restrict__ pool,
                                             const float* __restrict__ fc1W, const float* __restrict__ fc1b,
                                             const float* __restrict__ fc2W, const float* __restrict__ fc2b,
                                             const float* __restrict__ fc3W, const float* __restrict__ fc3b,
                                             float* __restrict__ out) {
  __shared__ float p[64], o1[128], o2[64], lg[10], red[2];
  int g = blockIdx.x, t = threadIdx.x;
  if (t < 64) p[t] = pool[(size_t)g * 64 + t];
  __syncthreads();
  {
    float a = fc1b[t];
    for (int k = 0; k < 64; ++k) a = fmaf(p[k], fc1W[k * 128 + t], a);
    o1[t] = fmaxf(a, 0.f);
  }
  __syncthreads();
  if (t < 64) {
    float a = fc2b[t];
    for (int k = 0; k < 128; ++k) a = fmaf(o1[k], fc2W[k * 64 + t], a);
    o2[t] = fmaxf(a, 0.f);
  }
  __syncthreads();
  if (t < 10) {
    float a = fc3b[t];
    for (int k = 0; k < 64; ++k) a = fmaf(o2[k], fc3W[k * 10 + t], a);
    lg[t] = a;
  }
  __syncthreads();
  if (t == 0) {
    float mx = lg[0];
    for (int j = 1; j < 10; ++j) mx = fmaxf(mx, lg[j]);
    float s = 0.f;
    for (int j = 0; j < 10; ++j) s += expf(lg[j] - mx);
    red[0] = mx;
    red[1] = logf(s);
  }
  __syncthreads();
  if (t < 10) out[(size_t)g * 10 + t] = lg[t] - red[0] - red[1];
}

// ---------------------------------------------------------------------------
extern "C" void kernel_launch(void* const* d_in, const int* in_sizes, int n_in,
                              void* d_out, int out_size, void* d_ws, size_t ws_size,
                              hipStream_t stream) {
  const float* x_in  = (const float*)d_in[0];
  const int*   ei    = (const int*)d_in[1];
  const int*   batch = (const int*)d_in[2];
  const float* W0    = (const float*)d_in[3];
  const float* b0    = (const float*)d_in[4];
  const float* cW1   = (const float*)d_in[5];
  const float* cb1   = (const float*)d_in[6];
  const float* gamma = (const float*)d_in[7];
  const float* beta  = (const float*)d_in[8];
  const float* cW2   = (const float*)d_in[9];
  const float* cb2   = (const float*)d_in[10];
  const float* fc1W  = (const float*)d_in[11];
  const float* fc1b  = (const float*)d_in[12];
  const float* fc2W  = (const float*)d_in[13];
  const float* fc2b  = (const float*)d_in[14];
  const float* fc3W  = (const float*)d_in[15];
  const float* fc3b  = (const float*)d_in[16];
  float* out = (float*)d_out;

  const int N = in_sizes[0] / 128;
  const int E = in_sizes[1] / 2;
  const int L = in_sizes[5] / (64 * 64);
  const int G = out_size / 10;
  const int* src = ei;
  const int* dst = ei + E;

  char* ws = (char*)d_ws;
  size_t off = 0;
  auto alloc = [&](size_t bytes) -> char* {
    char* p = ws + off;
    off += (bytes + 255) & ~(size_t)255;
    return p;
  };
  __half* X   = (__half*)alloc((size_t)N * 64 * 2);
  __half* Bf  = (__half*)alloc((size_t)N * 64 * 2);
  __half* zb0 = (__half*)alloc((size_t)N * 64 * 2);
  __half* zb1 = (__half*)alloc((size_t)N * 64 * 2);
  __half* zb2 = (__half*)alloc((size_t)N * 64 * 2);
  __half* W0T = (__half*)alloc((size_t)64 * 128 * 2);
  __half* W1T = (__half*)alloc((size_t)L * 64 * 64 * 2);
  __half* W2T = (__half*)alloc((size_t)L * 64 * 64 * 2);
  // ---- zeroed region: deg, pool, gstatAll (contiguous) ----
  int*   deg  = (int*)alloc((size_t)N * 4);
  float* pool = (float*)alloc((size_t)G * 64 * 4);
  float* gstatAll = (float*)alloc((size_t)3 * 128 * 4);
  char*  zero_end = ws + off;
  // ---------------------------------------------------------
  int*   rowptr = (int*)alloc((size_t)(N + 1) * 4);
  int*   cursor = (int*)alloc((size_t)N * 4);
  int*   csr    = (int*)alloc((size_t)E * 4);
  int*   bsum   = (int*)alloc(256 * 4);
  int*   boff   = (int*)alloc(256 * 4);
  __half* zbuf[3] = {zb0, zb1, zb2};

  hipMemsetAsync(deg, 0, (size_t)(zero_end - (char*)deg), stream);

  const int mmGrid    = (N + 63) / 64;
  const int edge4Grid = (E / 4 + 255) / 256 + 1;
  const int wcvtGrid  = (((L * 4096 > 8192) ? L * 4096 : 8192) + 255) / 256;

  // one-time weight conversion to fp16 transposed
  k_wcvt<<<wcvtGrid, 256, 0, stream>>>(W0, cW1, cW2, L, W0T, W1T, W2T);

  // X = relu(x @ W0 + b0) (fp16); Z1 = SCALING*project(X) (fp16)
  k_mm0<<<mmGrid, 256, 0, stream>>>(x_in, W0T, b0, X, zbuf[0], N);

  // CSR build
  k_deg<<<edge4Grid, 256, 0, stream>>>(dst, E, deg);
  const int NB = (N + 255) / 256;
  k_scan1<<<NB, 256, 0, stream>>>(deg, N, rowptr, bsum);
  k_scan2<<<1, 256, 0, stream>>>(bsum, NB, boff);
  k_scan3<<<NB, 256, 0, stream>>>(rowptr, boff, cursor, N, E);
  k_fill<<<edge4Grid, 256, 0, stream>>>(src, dst, E, cursor, csr);

  for (int i = 0; i < L; ++i) {
    float* gstat = gstatAll + (size_t)i * 128;
    const int last = (i == L - 1);
    k_layer1<<<mmGrid, 256, 0, stream>>>(X, rowptr, csr,
                                         W1T + (size_t)i * 4096, cb1 + i * 64,
                                         Bf, gstat, N);
    k_layer2<<<mmGrid, 256, 0, stream>>>(Bf, W2T + (size_t)i * 4096, cb2 + i * 64,
                                         gstat, gamma + i * 64, beta + i * 64,
                                         last ? nullptr : X,
                                         zbuf[i],
                                         (i == 0) ? nullptr : zbuf[i - 1],
                                         last ? nullptr : zbuf[i + 1],
                                         batch, pool, N);
  }

  k_mlp<<<G, 128, 0, stream>>>(pool, fc1W, fc1b, fc2W, fc2b, fc3W, fc3b, out);
}